// Round 4
// baseline (594.907 us; speedup 1.0000x reference)
//
#include <hip/hip_runtime.h>
#include <math.h>
#include <stdint.h>

#define B_ 8
#define T_ 2048
#define D_ 1024
#define H_ 1365
#define HPAD 1536
#define NTOK (B_*T_)
#define NSAMP 5
#define NRHO 5

typedef float  f32x4  __attribute__((ext_vector_type(4)));
typedef __bf16 bf16x8 __attribute__((ext_vector_type(8)));

// ---- ws layout (bytes) ----
#define WS_SCORES 0                              // f64 [16384]
#define WS_CNT    (WS_SCORES + NTOK*8)           // int [5*8*2048]
#define WS_PREDW  (WS_CNT + NRHO*B_*T_*4)        // f64 [5][8][1024]
#define WS_FULLW  (WS_PREDW + NRHO*B_*D_*8)      // f64 [8][1024]
#define WS_SUMEFF (WS_FULLW + B_*D_*8)           // f64 [5][8]
#define WS_SUMATT (WS_SUMEFF + NRHO*B_*8)        // f64 [8]
#define WS_SUMG   (WS_SUMATT + B_*8)             // f64 [5][8]
#define WS_ZERO_BYTES (WS_SUMG + NRHO*B_*8)
#define WS_STATS  (WS_SUMG + NRHO*B_*8)          // float2 [16384] (fallback path)
#define WS_W1THI  (WS_STATS + NTOK*8)            // ushort [1536][1024]
#define WS_W1TLO  (WS_W1THI + (size_t)HPAD*D_*2) // ushort [1536][1024]
#define WS_AHI    (WS_W1TLO + (size_t)HPAD*D_*2) // ushort [16384][1024]
#define WS_ALO    (WS_AHI + (size_t)NTOK*D_*2)   // ushort [16384][1024]
#define WS_FULL_END (WS_ALO + (size_t)NTOK*D_*2)

// ---- out layout (f32 elements) ----
#define OUT_G      0
#define OUT_GSW    16384
#define OUT_RECON  98304
#define OUT_LOSS   98305
#define OUT_RHOEFF 98310

__device__ inline unsigned short f2bf(float x) {   // RNE f32 -> bf16 bits
    uint32_t u = __float_as_uint(x);
    return (unsigned short)((u + 0x7FFFu + ((u >> 16) & 1u)) >> 16);
}

// ============================================================
// Prep: W1 [1024][1365] -> W1T hi/lo bf16 [1536][1024] (k-contiguous, zero-padded)
// ============================================================
__launch_bounds__(256)
__global__ void k_w1t(const float* __restrict__ W1, unsigned short* __restrict__ hi,
                      unsigned short* __restrict__ lo)
{
    __shared__ float tile[32][33];
    const int tid = threadIdx.x;
    const int bk = blockIdx.x & 31;
    const int bh = blockIdx.x >> 5;
    const int k0 = bk * 32, h0 = bh * 32;
    const int a = tid & 31, b = tid >> 5;
    #pragma unroll
    for (int i = 0; i < 4; ++i) {
        int k = k0 + b + i * 8;
        int h = h0 + a;
        tile[b + i*8][a] = (h < H_) ? W1[(size_t)k * H_ + h] : 0.0f;
    }
    __syncthreads();
    #pragma unroll
    for (int i = 0; i < 4; ++i) {
        int hrow = h0 + b + i * 8;
        int kcol = k0 + a;
        float v = tile[a][b + i*8];
        unsigned short hb = f2bf(v);
        float hf = __uint_as_float((uint32_t)hb << 16);
        unsigned short lb = f2bf(v - hf);
        size_t dst = (size_t)hrow * D_ + kcol;
        hi[dst] = hb; lo[dst] = lb;
    }
}

// ============================================================
// Prep: fused LN stats (f64) + f32 transform + bf16 hi/lo split -> Ahi/Alo
// ============================================================
__launch_bounds__(256)
__global__ void k_asplit(const float* __restrict__ emb, const float* __restrict__ attn,
                         const float* __restrict__ ln_g, const float* __restrict__ ln_b,
                         unsigned short* __restrict__ ahi, unsigned short* __restrict__ alo)
{
    const int tid = threadIdx.x, l = tid & 63, w = tid >> 6;
    const int t0 = blockIdx.x * 64;
    for (int tk = w; tk < 64; tk += 4) {
        const int tg = t0 + tk;
        const float av = attn[tg];
        const float* row = emb + (size_t)tg * D_;
        float rv[16];
        double s1 = 0.0, s2 = 0.0;
        #pragma unroll
        for (int i = 0; i < 16; ++i) {
            rv[i] = row[i*64 + l];
            double x = (double)rv[i] * (double)av;
            s1 += x; s2 += x * x;
        }
        for (int m = 32; m; m >>= 1) { s1 += __shfl_xor(s1, m); s2 += __shfl_xor(s2, m); }
        double mean = s1 / (double)D_;
        double var  = s2 / (double)D_ - mean * mean;
        double inv  = 1.0 / sqrt(var + 1e-5);
        float sc  = (float)((double)av * inv);
        float nsh = -(float)(mean * inv);
        #pragma unroll
        for (int i = 0; i < 16; ++i) {
            int k = i * 64 + l;
            float t  = fmaf(rv[i], sc, nsh);
            float xn = fmaf(t, ln_g[k], ln_b[k]);
            unsigned short hb = f2bf(xn);
            float hf = __uint_as_float((uint32_t)hb << 16);
            size_t dst = (size_t)tg * D_ + k;
            ahi[dst] = hb;
            alo[dst] = f2bf(xn - hf);
        }
    }
}

// (fallback path prep: per-token stats only)
__launch_bounds__(256)
__global__ void k_stats(const float* __restrict__ emb, const float* __restrict__ attn,
                        float2* __restrict__ stats)
{
    const int tid = threadIdx.x, l = tid & 63, w = tid >> 6;
    const int t0 = blockIdx.x * 64;
    for (int tk = w; tk < 64; tk += 4) {
        const int tg = t0 + tk;
        const float av = attn[tg];
        const float* row = emb + (size_t)tg * D_;
        double s1 = 0.0, s2 = 0.0;
        #pragma unroll
        for (int i = 0; i < D_/64; ++i) {
            double x = (double)row[i*64 + l] * (double)av;
            s1 += x; s2 += x * x;
        }
        for (int m = 32; m; m >>= 1) { s1 += __shfl_xor(s1, m); s2 += __shfl_xor(s2, m); }
        if (l == 0) {
            double mean = s1 / (double)D_;
            double var  = s2 / (double)D_ - mean * mean;
            double inv  = 1.0 / sqrt(var + 1e-5);
            stats[tg] = make_float2((float)((double)av * inv), (float)(mean * inv));
        }
    }
}

// ============================================================
// Kernel A: 3-term split GEMM, A-only LDS + B direct-to-register
//
// BM=128, BN=256, BK=32, 512 thr (8 waves 2Mx4N, 64x64/wave, 4x4 16x16x32 frags).
// Grid 768 = 128 M-tiles x 6 N-tiles (HPAD=1536) = exactly 3 rounds of 256 CUs.
//
// R4 change (post-mortem: LDS pipe ~2000cy/step was co-dominant with MFMA
// 1862cy and the per-step barrier phase-aligns them -> serialized, 44%
// MfmaUtil): remove B from LDS. B (6 MB, L2-resident; 16KB/step unique,
// wr-pair waves share frags -> L1 hits) is loaded global->register,
// double-buffered 1 step ahead. A stays in LDS (4x inter-wave sharing):
// 4-deep ring of 16 KB (Ahi 8K | Alo 8K), DMA distance 3, 64 KiB total.
// LDS/step drops 176KB -> 80KB (~950cy << MFMA 1862cy).
// All MFMA operands are in regs at burst start (A via cross-step ds_read
// prefetch, B via global prefetch). One vmcnt(2) + one barrier per step;
// only this step's 2 A-DMAs stay in flight across the barrier.
// Ring hazard audit: DMA(t)->buf[(t+3)&3]==buf[(t-1)&3]; its last reads
// were the prefetch during step t-2 -> two barriers before DMA. Safe.
// Staging swizzle unchanged: inverse-swizzled SOURCE + swizzled ds_read,
// slot ^= (row>>1)&3 (16B units) -> 0 bank conflicts.
// ============================================================
#define ABUF_U 8192          // ushorts per A buffer (Ahi 4096 | Alo 4096)
#define KSTEPS 32

__device__ __forceinline__ void gll16(const unsigned short* g, unsigned short* l)
{
    __builtin_amdgcn_global_load_lds((const __attribute__((address_space(1))) void*)g,
                                     (__attribute__((address_space(3))) void*)l, 16, 0, 0);
}

__launch_bounds__(512, 2)
__global__ void k_scores8(const unsigned short* __restrict__ ahi,
                          const unsigned short* __restrict__ alo,
                          const unsigned short* __restrict__ w1thi,
                          const unsigned short* __restrict__ w1tlo,
                          const float* __restrict__ b1, const float* __restrict__ W2,
                          double* __restrict__ scores)
{
    __shared__ __align__(16) unsigned short smem[4*ABUF_U];   // 64 KiB

    const int tid = threadIdx.x;
    const int blk = blockIdx.x;
    // XCD-aware swizzle: 768 blocks, 8 XCDs, 96/XCD; hh fastest within chunk
    const int lin = (blk & 7) * 96 + (blk >> 3);
    const int mm = lin / 6, hh = lin - mm * 6;
    const int t0 = mm * 128;
    const int h0 = hh * 256;

    const int l  = tid & 63, w = tid >> 6;
    const int wr = w >> 2, wcn = w & 3;            // wave row/col group
    const int lm = l & 15, lq = l >> 4;

    // ---- A staging: per-lane global src (inverse-swizzled), wave-uniform LDS dst
    const int lrow  = l >> 2;                      // 0..15 within 16-row chunk
    const int lslot = (l & 3) ^ ((l >> 3) & 3);    // logical 16B slot for phys slot l&3
    const unsigned short* sA_hi = ahi + (size_t)(t0 + w*16 + lrow) * D_ + lslot*8;
    const unsigned short* sA_lo = alo + (size_t)(t0 + w*16 + lrow) * D_ + lslot*8;
    const int dA = w*512;                          // buffer-relative A-hi dst (ushorts)

    // ---- A fragment read offsets (swizzled): phys_slot = lq ^ ((row>>1)&3)
    const int sw8 = (lq ^ ((lm >> 1) & 3)) * 8;
    int offA[4];
    #pragma unroll
    for (int r = 0; r < 4; ++r) offA[r] = (wr*64 + r*16 + lm)*32 + sw8;

    // ---- B fragment global base (per-lane): row = h0+wcn*64+c*16+lm, slot lq
    const unsigned short* bBh = w1thi + (size_t)(h0 + wcn*64 + lm) * D_ + lq*8;
    const unsigned short* bBl = w1tlo + (size_t)(h0 + wcn*64 + lm) * D_ + lq*8;

    f32x4 acc[4][4];
    #pragma unroll
    for (int r = 0; r < 4; ++r)
        #pragma unroll
        for (int c = 0; c < 4; ++c) acc[r][c] = (f32x4){0.f, 0.f, 0.f, 0.f};

    // ---- prologue: DMA A(0),A(1),A(2) -> bufs 0,1,2; B(0) direct; drain; frags(0)
    gll16(sA_hi,      &smem[0*ABUF_U + dA]);
    gll16(sA_lo,      &smem[0*ABUF_U + dA + 4096]);
    gll16(sA_hi + 32, &smem[1*ABUF_U + dA]);
    gll16(sA_lo + 32, &smem[1*ABUF_U + dA + 4096]);
    gll16(sA_hi + 64, &smem[2*ABUF_U + dA]);
    gll16(sA_lo + 64, &smem[2*ABUF_U + dA + 4096]);
    bf16x8 ahp[2][4], alp[2][4], bhp[2][4], blp[2][4];
    #pragma unroll
    for (int c = 0; c < 4; ++c) {
        bhp[0][c] = *(const bf16x8*)&bBh[(size_t)c*16*D_];
        blp[0][c] = *(const bf16x8*)&bBl[(size_t)c*16*D_];
    }
    asm volatile("s_waitcnt vmcnt(0)" ::: "memory");
    asm volatile("s_barrier" ::: "memory");
    #pragma unroll
    for (int r = 0; r < 4; ++r) {
        ahp[0][r] = *(const bf16x8*)&smem[offA[r]];
        alp[0][r] = *(const bf16x8*)&smem[4096 + offA[r]];
    }

    #pragma unroll
    for (int t = 0; t < KSTEPS; ++t) {
        const int cur = t & 1, nxt = (t + 1) & 1;
        // B prefetch (global->reg) for step t+1
        if (t + 1 < KSTEPS) {
            #pragma unroll
            for (int c = 0; c < 4; ++c) {
                bhp[nxt][c] = *(const bf16x8*)&bBh[(size_t)c*16*D_ + (t+1)*32];
                blp[nxt][c] = *(const bf16x8*)&bBl[(size_t)c*16*D_ + (t+1)*32];
            }
        }
        // A DMA for step t+3 (ring slot (t+3)&3 == (t-1)&3: last read at t-2)
        if (t + 3 < KSTEPS) {
            const int ab = ((t + 3) & 3) * ABUF_U;
            gll16(sA_hi + (t+3)*32, &smem[ab + dA]);
            gll16(sA_lo + (t+3)*32, &smem[ab + dA + 4096]);
        }
        // A fragment prefetch (LDS->reg) for step t+1
        if (t + 1 < KSTEPS) {
            const int ab = ((t + 1) & 3) * ABUF_U;
            #pragma unroll
            for (int r = 0; r < 4; ++r) {
                ahp[nxt][r] = *(const bf16x8*)&smem[ab + offA[r]];
                alp[nxt][r] = *(const bf16x8*)&smem[ab + 4096 + offA[r]];
            }
        }
        // MFMA burst: all operands in registers
        __builtin_amdgcn_s_setprio(1);
        #pragma unroll
        for (int r = 0; r < 4; ++r)
            #pragma unroll
            for (int c = 0; c < 4; ++c)
                acc[r][c] = __builtin_amdgcn_mfma_f32_16x16x32_bf16(ahp[cur][r], bhp[cur][c], acc[r][c], 0, 0, 0);
        #pragma unroll
        for (int r = 0; r < 4; ++r)
            #pragma unroll
            for (int c = 0; c < 4; ++c)
                acc[r][c] = __builtin_amdgcn_mfma_f32_16x16x32_bf16(ahp[cur][r], blp[cur][c], acc[r][c], 0, 0, 0);
        #pragma unroll
        for (int r = 0; r < 4; ++r)
            #pragma unroll
            for (int c = 0; c < 4; ++c)
                acc[r][c] = __builtin_amdgcn_mfma_f32_16x16x32_bf16(alp[cur][r], bhp[cur][c], acc[r][c], 0, 0, 0);
        __builtin_amdgcn_s_setprio(0);
        // drain: keep only this step's 2 A-DMAs in flight (B-loads issued
        // earlier this step drain too -> B(t+1) certainly ready)
        if (t < KSTEPS - 3) asm volatile("s_waitcnt vmcnt(2)" ::: "memory");
        else                asm volatile("s_waitcnt vmcnt(0)" ::: "memory");
        if (t < KSTEPS - 1) asm volatile("s_barrier" ::: "memory");
    }

    // ---- epilogue: bias + GELU + W2 dot, f64 reduce over h, atomic into scores
    float b1v[4], w2v[4];
    #pragma unroll
    for (int c = 0; c < 4; ++c) {
        int hg = h0 + wcn*64 + c*16 + lm;
        bool ok = (hg < H_);
        b1v[c] = ok ? b1[hg] : 0.0f;
        w2v[c] = ok ? W2[hg] : 0.0f;
    }
    const float is2 = 0.70710678118654752440f;
    #pragma unroll
    for (int r = 0; r < 4; ++r) {
        #pragma unroll
        for (int i = 0; i < 4; ++i) {
            float ps = 0.0f;
            #pragma unroll
            for (int c = 0; c < 4; ++c) {
                float z  = acc[r][c][i] + b1v[c];
                float gl = 0.5f * z * (1.0f + erff(z * is2));
                ps = fmaf(gl, w2v[c], ps);
            }
            double psd = (double)ps;
            psd += __shfl_xor(psd, 1);
            psd += __shfl_xor(psd, 2);
            psd += __shfl_xor(psd, 4);
            psd += __shfl_xor(psd, 8);
            if (lm == 0)
                atomicAdd(&scores[t0 + wr*64 + r*16 + lq*4 + i], psd);
        }
    }
}

// ============================================================
// Kernel A (fallback, smaller-ws version): in-loop LN+split staging
// ============================================================
__launch_bounds__(256)
__global__ void k_scores_fb(const float* __restrict__ emb, const float* __restrict__ ln_g,
                            const float* __restrict__ ln_b, const float2* __restrict__ stats,
                            const unsigned short* __restrict__ w1thi,
                            const unsigned short* __restrict__ w1tlo,
                            const float* __restrict__ b1, const float* __restrict__ W2,
                            double* __restrict__ scores)
{
    __shared__ __align__(16) unsigned short sAhi[128*40];
    __shared__ __align__(16) unsigned short sAlo[128*40];
    __shared__ __align__(16) unsigned short sBhi[128*40];
    __shared__ __align__(16) unsigned short sBlo[128*40];
    __shared__ float sS1[128], sS2[128];

    const int tid = threadIdx.x;
    const int blk = blockIdx.x;
    const int xcd = blk & 7, slot = blk >> 3;
    const int lin = xcd * 176 + slot;
    const int tt = lin / 11, hh = lin - tt * 11;
    const int t0 = tt * 128;
    const int h0 = hh * 128;

    if (tid < 128) {
        float2 st = stats[t0 + tid];
        sS1[tid] = st.x; sS2[tid] = st.y;
    }
    f32x4 acc[4][4];
    #pragma unroll
    for (int r = 0; r < 4; ++r)
        #pragma unroll
        for (int c = 0; c < 4; ++c) acc[r][c] = (f32x4){0.f, 0.f, 0.f, 0.f};
    const int l = tid & 63, w = tid >> 6;
    const int lm = l & 15, lq = l >> 4;
    const int wr = (w >> 1) * 64;
    const int wc = (w & 1) * 64;
    __syncthreads();

    for (int kc = 0; kc < D_; kc += 32) {
        #pragma unroll
        for (int r2 = 0; r2 < 2; ++r2) {
            int g = tid + r2 * 256;
            int row = g >> 2, oct = g & 3;
            size_t src = (size_t)(h0 + row) * D_ + kc + oct * 8;
            int dst = row * 40 + oct * 8;
            *(bf16x8*)&sBhi[dst] = *(const bf16x8*)&w1thi[src];
            *(bf16x8*)&sBlo[dst] = *(const bf16x8*)&w1tlo[src];
        }
        #pragma unroll
        for (int r2 = 0; r2 < 2; ++r2) {
            int g = tid + r2 * 256;
            int tk = g >> 2, oct = g & 3;
            int tg = t0 + tk, dg = kc + oct * 8;
            const float* ep = emb + (size_t)tg * D_ + dg;
            float s1 = sS1[tk], ns2 = -sS2[tk];
            union { unsigned short s[8]; bf16x8 v; } hi, lo;
            #pragma unroll
            for (int j = 0; j < 8; ++j) {
                float t  = fmaf(ep[j], s1, ns2);
                float xn = fmaf(t, ln_g[dg + j], ln_b[dg + j]);
                unsigned short hb = f2bf(xn);
                float hf = __uint_as_float((uint32_t)hb << 16);
                hi.s[j] = hb;
                lo.s[j] = f2bf(xn - hf);
            }
            int dst = tk * 40 + oct * 8;
            *(bf16x8*)&sAhi[dst] = hi.v;
            *(bf16x8*)&sAlo[dst] = lo.v;
        }
        __syncthreads();
        bf16x8 ah[4], al[4], bh[4], bl[4];
        #pragma unroll
        for (int r = 0; r < 4; ++r) {
            int off = (wr + r * 16 + lm) * 40 + lq * 8;
            ah[r] = *(const bf16x8*)&sAhi[off];
            al[r] = *(const bf16x8*)&sAlo[off];
        }
        #pragma unroll
        for (int c = 0; c < 4; ++c) {
            int off = (wc + c * 16 + lm) * 40 + lq * 8;
            bh[c] = *(const bf16x8*)&sBhi[off];
            bl[c] = *(const bf16x8*)&sBlo[off];
        }
        #pragma unroll
        for (int r = 0; r < 4; ++r)
            #pragma unroll
            for (int c = 0; c < 4; ++c) {
                acc[r][c] = __builtin_amdgcn_mfma_f32_16x16x32_bf16(ah[r], bh[c], acc[r][c], 0, 0, 0);
                acc[r][c] = __builtin_amdgcn_mfma_f32_16x16x32_bf16(ah[r], bl[c], acc[r][c], 0, 0, 0);
                acc[r][c] = __builtin_amdgcn_mfma_f32_16x16x32_bf16(al[r], bh[c], acc[r][c], 0, 0, 0);
            }
        __syncthreads();
    }
    float b1v[4], w2v[4];
    #pragma unroll
    for (int c = 0; c < 4; ++c) {
        int hg = h0 + wc + c * 16 + lm;
        bool ok = (hg < H_);
        b1v[c] = ok ? b1[hg] : 0.0f;
        w2v[c] = ok ? W2[hg] : 0.0f;
    }
    const float is2 = 0.70710678118654752440f;
    #pragma unroll
    for (int r = 0; r < 4; ++r) {
        #pragma unroll
        for (int i = 0; i < 4; ++i) {
            float ps = 0.0f;
            #pragma unroll
            for (int c = 0; c < 4; ++c) {
                float z  = acc[r][c][i] + b1v[c];
                float gl = 0.5f * z * (1.0f + erff(z * is2));
                ps = fmaf(gl, w2v[c], ps);
            }
            double psd = (double)ps;
            psd += __shfl_xor(psd, 1);
            psd += __shfl_xor(psd, 2);
            psd += __shfl_xor(psd, 4);
            psd += __shfl_xor(psd, 8);
            if (lm == 0)
                atomicAdd(&scores[t0 + wr + r * 16 + lq * 4 + i], psd);
        }
    }
}

// ============================================================
// JAX threefry2x32
// ============================================================
__device__ inline void tf2x32(uint32_t k0, uint32_t k1, uint32_t x0, uint32_t x1,
                              uint32_t& o0, uint32_t& o1)
{
    const uint32_t ks2 = k0 ^ k1 ^ 0x1BD11BDAu;
    x0 += k0; x1 += k1;
#define ROT_(v,d) (((v) << (d)) | ((v) >> (32 - (d))))
#define RND_(R) { x0 += x1; x1 = ROT_(x1, R); x1 ^= x0; }
    RND_(13) RND_(15) RND_(26) RND_(6)
    x0 += k1;  x1 += ks2 + 1u;
    RND_(17) RND_(29) RND_(16) RND_(24)
    x0 += ks2; x1 += k0 + 2u;
    RND_(13) RND_(15) RND_(26) RND_(6)
    x0 += k0;  x1 += k1 + 3u;
    RND_(17) RND_(29) RND_(16) RND_(24)
    x0 += k1;  x1 += ks2 + 4u;
    RND_(13) RND_(15) RND_(26) RND_(6)
    x0 += ks2; x1 += k0 + 5u;
    o0 = x0; o1 = x1;
#undef RND_
#undef ROT_
}

// ============================================================
// Kernel B: gumbel pert + MSB radix-select k-th largest + indicator counts
// ============================================================
__launch_bounds__(256)
__global__ void k_topk(const double* __restrict__ scores, const float* __restrict__ attn,
                       const float* __restrict__ b2, int* __restrict__ cnt)
{
    __shared__ unsigned long long keys[2048];
    __shared__ unsigned int hist[256];
    __shared__ unsigned int wsum[4];
    __shared__ unsigned int selDigit, selBase;
    __shared__ double red[4];

    const int tid = threadIdx.x;
    const int blk = blockIdx.x;
    const int j = blk / 40;
    const int s = (blk % 40) >> 3;
    const int b = blk & 7;

    uint32_t kk0, kk1;
    tf2x32(0u, 42u, 0u, (uint32_t)j, kk0, kk1);

    double tsum = 0.0;
    for (int t = tid; t < T_; t += 256) tsum += (double)attn[b * T_ + t];
    for (int m = 32; m; m >>= 1) tsum += __shfl_xor(tsum, m);
    if ((tid & 63) == 0) red[tid >> 6] = tsum;
    __syncthreads();
    const double Teff = red[0] + red[1] + red[2] + red[3];
    const float rhos[5] = {0.1f, 0.2f, 0.3f, 0.4f, 0.5f};
    int kst = (int)(rhos[j] * (float)Teff);
    if (kst < 1) kst = 1;

    const double bb2 = (double)b2[0];
    #pragma unroll
    for (int r = 0; r < 8; ++r) {
        int t = tid + r * 256;
        int f = (s * 8 + b) * T_ + t;
        uint32_t o0, o1;
        tf2x32(kk0, kk1, 0u, (uint32_t)f, o0, o1);
        uint32_t bits = o0 ^ o1;
        float u = __uint_as_float((bits >> 9) | 0x3f800000u) - 1.0f;
        float a1 = (float)((double)u + (double)1e-6f);
        float la = (float)log((double)a1);
        float m1 = (float)((double)1e-6f - (double)la);
        float lb = (float)log((double)m1);
        float noise = -lb;
        float av = attn[b * T_ + t];
        double pv = (av == 0.0f) ? -1e9 : (scores[b * T_ + t] + bb2 + (double)noise);
        unsigned long long uu = (unsigned long long)__double_as_longlong(pv);
        keys[t] = (uu >> 63) ? ~uu : (uu | 0x8000000000000000ull);
    }
    __syncthreads();

    unsigned long long pfx = 0;
    unsigned int plo = (unsigned int)(2048 - kst);
    const int lane = tid & 63, wv = tid >> 6;
    for (int pass = 0; pass < 8; ++pass) {
        const int shift = 56 - 8 * pass;
        const unsigned long long maskhi = (pass == 0) ? 0ull : (~0ull << (64 - 8 * pass));
        hist[tid] = 0;
        __syncthreads();
        #pragma unroll
        for (int r = 0; r < 8; ++r) {
            unsigned long long kk = keys[tid + r * 256];
            if ((kk & maskhi) == pfx)
                atomicAdd(&hist[(unsigned int)((kk >> shift) & 255ull)], 1u);
        }
        __syncthreads();
        unsigned int own = hist[tid];
        int val = (int)own;
        #pragma unroll
        for (int off = 1; off < 64; off <<= 1) {
            int n = __shfl_up(val, off);
            if (lane >= off) val += n;
        }
        if (lane == 63) wsum[wv] = (unsigned int)val;
        __syncthreads();
        unsigned int woff = 0;
        for (int q = 0; q < wv; ++q) woff += wsum[q];
        unsigned int incl = (unsigned int)val + woff;
        unsigned int excl = incl - own;
        if (own > 0 && plo >= excl && plo < incl) { selDigit = (unsigned int)tid; selBase = excl; }
        __syncthreads();
        pfx |= ((unsigned long long)selDigit << shift);
        plo -= selBase;
        __syncthreads();
    }

    #pragma unroll
    for (int r = 0; r < 8; ++r) {
        int t = tid + r * 256;
        if (keys[t] >= pfx) atomicAdd(&cnt[(j * 8 + b) * T_ + t], 1);
    }
}

// ============================================================
// Kernel C: finalize g = cnt/5, write g & g_sweep & rho_eff, row sums
// ============================================================
__launch_bounds__(256)
__global__ void k_gfin(const int* __restrict__ cnt, const float* __restrict__ attn,
                       float* __restrict__ out, double* __restrict__ sumeff,
                       double* __restrict__ sumatt, double* __restrict__ sumg)
{
    __shared__ double redA[4], redB[4], redC[4];
    const int j = blockIdx.x >> 3, b = blockIdx.x & 7;
    const int tid = threadIdx.x;
    double sg = 0.0, se = 0.0, sa = 0.0;
    for (int t = tid; t < T_; t += 256) {
        int c = cnt[(j * 8 + b) * T_ + t];
        float g  = (float)c / 5.0f;
        float av = attn[b * T_ + t];
        out[OUT_GSW + (j * 8 + b) * T_ + t] = g;
        if (j == 4) out[OUT_G + b * T_ + t] = g;
        sg += (double)g;
        se += (double)(av * g);
        sa += (double)av;
    }
    for (int m = 32; m; m >>= 1) { sg += __shfl_xor(sg, m); se += __shfl_xor(se, m); sa += __shfl_xor(sa, m); }
    if ((tid & 63) == 0) { redA[tid>>6] = sg; redB[tid>>6] = se; redC[tid>>6] = sa; }
    __syncthreads();
    if (tid == 0) {
        sg = redA[0]+redA[1]+redA[2]+redA[3];
        se = redB[0]+redB[1]+redB[2]+redB[3];
        sa = redC[0]+redC[1]+redC[2]+redC[3];
        sumg[j*8+b] = sg; sumeff[j*8+b] = se;
        if (j == 0) sumatt[b] = sa;
        out[OUT_RHOEFF + j*8 + b] = (float)sg / (float)sa;
    }
}

// ============================================================
// Kernel D: pooled weighted sums over tok = emb_table[ids] (512 blocks)
// ============================================================
__launch_bounds__(256)
__global__ void k_pool(const int* __restrict__ ids, const float* __restrict__ attn,
                       const float* __restrict__ out, const float* __restrict__ emb_table,
                       double* __restrict__ predw, double* __restrict__ fullw)
{
    __shared__ int   sid[128];
    __shared__ float sw[6][128];
    const int blk = blockIdx.x;
    const int b  = blk >> 6;            // 8
    const int dc = (blk >> 4) & 3;      // 4
    const int tc = blk & 15;            // 16
    const int tid = threadIdx.x;
    const int d = dc * 256 + tid;
    if (tid < 128) {
        int t = tc * 128 + tid;
        sid[tid] = ids[b * T_ + t];
        float av = attn[b * T_ + t];
        sw[0][tid] = av;
        #pragma unroll
        for (int j = 0; j < 5; ++j) {
            float g = out[OUT_GSW + (j * 8 + b) * T_ + t];
            sw[1 + j][tid] = av * g;
        }
    }
    __syncthreads();
    double acc[6] = {0,0,0,0,0,0};
    for (int i = 0; i < 128; ++i) {
        float val = emb_table[(size_t)sid[i] * D_ + d];
        #pragma unroll
        for (int c = 0; c < 6; ++c) acc[c] += (double)(val * sw[c][i]);
    }
    atomicAdd(&fullw[b * D_ + d], acc[0]);
    #pragma unroll
    for (int j = 0; j < 5; ++j)
        atomicAdd(&predw[(j * 8 + b) * D_ + d], acc[1 + j]);
}

// ============================================================
// Kernel E: losses (single block)
// ============================================================
__launch_bounds__(256)
__global__ void k_loss(const double* __restrict__ predw, const double* __restrict__ fullw,
                       const double* __restrict__ sumeff, const double* __restrict__ sumatt,
                       float* __restrict__ out)
{
    __shared__ double red[4];
    __shared__ float lr[5];
    const int tid = threadIdx.x;
    for (int j = 0; j < 5; ++j) {
        double p = 0.0;
        for (int i = tid; i < B_ * D_; i += 256) {
            int b = i >> 10;
            double dF = sumatt[b];        if (dF < 1e-6) dF = 1e-6;
            double dE = sumeff[j*8 + b];  if (dE < 1e-6) dE = 1e-6;
            double diff = predw[j * B_ * D_ + i] / dE - fullw[i] / dF;
            p += diff * diff;
        }
        for (int m = 32; m; m >>= 1) p += __shfl_xor(p, m);
        if ((tid & 63) == 0) red[tid >> 6] = p;
        __syncthreads();
        if (tid == 0) {
            double t = red[0] + red[1] + red[2] + red[3];
            lr[j] = (float)(t / (double)(B_ * D_));
            out[OUT_LOSS + j] = lr[j];
        }
        __syncthreads();
    }
    if (tid == 0) {
        float srec = 0.0f;
        for (int j = 0; j < 5; ++j) srec += lr[j];
        out[OUT_RECON] = srec / 5.0f;
    }
}

extern "C" void kernel_launch(void* const* d_in, const int* in_sizes, int n_in,
                              void* d_out, int out_size, void* d_ws, size_t ws_size,
                              hipStream_t stream)
{
    const int*   ids  = (const int*)  d_in[0];
    const float* emb  = (const float*)d_in[1];
    const float* attn = (const float*)d_in[2];
    const float* ln_g = (const float*)d_in[3];
    const float* ln_b = (const float*)d_in[4];
    const float* W1   = (const float*)d_in[5];
    const float* b1   = (const float*)d_in[6];
    const float* W2   = (const float*)d_in[7];
    const float* b2   = (const float*)d_in[8];
    const float* et   = (const float*)d_in[9];
    float* out = (float*)d_out;
    char*  ws  = (char*)d_ws;

    double* scores = (double*)(ws + WS_SCORES);
    int*    cnt    = (int*)   (ws + WS_CNT);
    double* predw  = (double*)(ws + WS_PREDW);
    double* fullw  = (double*)(ws + WS_FULLW);
    double* sumeff = (double*)(ws + WS_SUMEFF);
    double* sumatt = (double*)(ws + WS_SUMATT);
    double* sumg   = (double*)(ws + WS_SUMG);
    float2* stats  = (float2*)(ws + WS_STATS);
    unsigned short* w1thi = (unsigned short*)(ws + WS_W1THI);
    unsigned short* w1tlo = (unsigned short*)(ws + WS_W1TLO);
    unsigned short* ahi   = (unsigned short*)(ws + WS_AHI);
    unsigned short* alo   = (unsigned short*)(ws + WS_ALO);

    hipMemsetAsync(d_ws, 0, WS_ZERO_BYTES, stream);

    k_w1t<<<48*32, 256, 0, stream>>>(W1, w1thi, w1tlo);
    if (ws_size >= WS_FULL_END) {
        k_asplit<<<NTOK/64, 256, 0, stream>>>(emb, attn, ln_g, ln_b, ahi, alo);
        k_scores8<<<768, 512, 0, stream>>>(ahi, alo, w1thi, w1tlo, b1, W2, scores);
    } else {
        k_stats<<<NTOK/64, 256, 0, stream>>>(emb, attn, stats);
        k_scores_fb<<<1408, 256, 0, stream>>>(emb, ln_g, ln_b, stats, w1thi, w1tlo,
                                              b1, W2, scores);
    }
    k_topk<<<NRHO * NSAMP * B_, 256, 0, stream>>>(scores, attn, b2, cnt);
    k_gfin<<<NRHO * B_, 256, 0, stream>>>(cnt, attn, out, sumeff, sumatt, sumg);
    k_pool<<<512, 256, 0, stream>>>(ids, attn, out, et, predw, fullw);
    k_loss<<<1, 256, 0, stream>>>(predw, fullw, sumeff, sumatt, out);
}

// Round 6
// 575.633 us; speedup vs baseline: 1.0335x; 1.0335x over previous
//
#include <hip/hip_runtime.h>
#include <math.h>
#include <stdint.h>

#define B_ 8
#define T_ 2048
#define D_ 1024
#define H_ 1365
#define HPAD 1536
#define NTOK (B_*T_)
#define NSAMP 5
#define NRHO 5

typedef float  f32x4  __attribute__((ext_vector_type(4)));
typedef __bf16 bf16x8 __attribute__((ext_vector_type(8)));

// ---- ws layout (bytes) ----
#define WS_SCORES 0                              // f64 [16384]
#define WS_CNT    (WS_SCORES + NTOK*8)           // int [5*8*2048]
#define WS_PREDW  (WS_CNT + NRHO*B_*T_*4)        // f64 [5][8][1024]
#define WS_FULLW  (WS_PREDW + NRHO*B_*D_*8)      // f64 [8][1024]
#define WS_SUMEFF (WS_FULLW + B_*D_*8)           // f64 [5][8]
#define WS_SUMATT (WS_SUMEFF + NRHO*B_*8)        // f64 [8]
#define WS_SUMG   (WS_SUMATT + B_*8)             // f64 [5][8]
#define WS_LR     (WS_SUMG + NRHO*B_*8)          // f64 [5]
#define WS_ZERO_BYTES (WS_LR + NRHO*8)
#define WS_STATS  WS_ZERO_BYTES                  // float2 [16384] (fallback path)
#define WS_W1THI  (WS_STATS + NTOK*8)            // ushort [1536][1024]
#define WS_W1TLO  (WS_W1THI + (size_t)HPAD*D_*2) // ushort [1536][1024]
#define WS_AHI    (WS_W1TLO + (size_t)HPAD*D_*2) // ushort [16384][1024]
#define WS_ALO    (WS_AHI + (size_t)NTOK*D_*2)   // ushort [16384][1024]
#define WS_FULL_END (WS_ALO + (size_t)NTOK*D_*2)

// ---- out layout (f32 elements) ----
#define OUT_G      0
#define OUT_GSW    16384
#define OUT_RECON  98304
#define OUT_LOSS   98305
#define OUT_RHOEFF 98310

__device__ inline unsigned short f2bf(float x) {   // RNE f32 -> bf16 bits
    uint32_t u = __float_as_uint(x);
    return (unsigned short)((u + 0x7FFFu + ((u >> 16) & 1u)) >> 16);
}

// ============================================================
// Prep: W1 [1024][1365] -> W1T hi/lo bf16 [1536][1024] (k-contiguous, zero-padded)
// ============================================================
__launch_bounds__(256)
__global__ void k_w1t(const float* __restrict__ W1, unsigned short* __restrict__ hi,
                      unsigned short* __restrict__ lo)
{
    __shared__ float tile[32][33];
    const int tid = threadIdx.x;
    const int bk = blockIdx.x & 31;
    const int bh = blockIdx.x >> 5;
    const int k0 = bk * 32, h0 = bh * 32;
    const int a = tid & 31, b = tid >> 5;
    #pragma unroll
    for (int i = 0; i < 4; ++i) {
        int k = k0 + b + i * 8;
        int h = h0 + a;
        tile[b + i*8][a] = (h < H_) ? W1[(size_t)k * H_ + h] : 0.0f;
    }
    __syncthreads();
    #pragma unroll
    for (int i = 0; i < 4; ++i) {
        int hrow = h0 + b + i * 8;
        int kcol = k0 + a;
        float v = tile[a][b + i*8];
        unsigned short hb = f2bf(v);
        float hf = __uint_as_float((uint32_t)hb << 16);
        unsigned short lb = f2bf(v - hf);
        size_t dst = (size_t)hrow * D_ + kcol;
        hi[dst] = hb; lo[dst] = lb;
    }
}

// ============================================================
// Prep: fused LN stats (f64) + f32 transform + bf16 hi/lo split -> Ahi/Alo
// ============================================================
__launch_bounds__(256)
__global__ void k_asplit(const float* __restrict__ emb, const float* __restrict__ attn,
                         const float* __restrict__ ln_g, const float* __restrict__ ln_b,
                         unsigned short* __restrict__ ahi, unsigned short* __restrict__ alo)
{
    const int tid = threadIdx.x, l = tid & 63, w = tid >> 6;
    const int t0 = blockIdx.x * 64;
    for (int tk = w; tk < 64; tk += 4) {
        const int tg = t0 + tk;
        const float av = attn[tg];
        const float* row = emb + (size_t)tg * D_;
        float rv[16];
        double s1 = 0.0, s2 = 0.0;
        #pragma unroll
        for (int i = 0; i < 16; ++i) {
            rv[i] = row[i*64 + l];
            double x = (double)rv[i] * (double)av;
            s1 += x; s2 += x * x;
        }
        for (int m = 32; m; m >>= 1) { s1 += __shfl_xor(s1, m); s2 += __shfl_xor(s2, m); }
        double mean = s1 / (double)D_;
        double var  = s2 / (double)D_ - mean * mean;
        double inv  = 1.0 / sqrt(var + 1e-5);
        float sc  = (float)((double)av * inv);
        float nsh = -(float)(mean * inv);
        #pragma unroll
        for (int i = 0; i < 16; ++i) {
            int k = i * 64 + l;
            float t  = fmaf(rv[i], sc, nsh);
            float xn = fmaf(t, ln_g[k], ln_b[k]);
            unsigned short hb = f2bf(xn);
            float hf = __uint_as_float((uint32_t)hb << 16);
            size_t dst = (size_t)tg * D_ + k;
            ahi[dst] = hb;
            alo[dst] = f2bf(xn - hf);
        }
    }
}

// (fallback path prep: per-token stats only)
__launch_bounds__(256)
__global__ void k_stats(const float* __restrict__ emb, const float* __restrict__ attn,
                        float2* __restrict__ stats)
{
    const int tid = threadIdx.x, l = tid & 63, w = tid >> 6;
    const int t0 = blockIdx.x * 64;
    for (int tk = w; tk < 64; tk += 4) {
        const int tg = t0 + tk;
        const float av = attn[tg];
        const float* row = emb + (size_t)tg * D_;
        double s1 = 0.0, s2 = 0.0;
        #pragma unroll
        for (int i = 0; i < D_/64; ++i) {
            double x = (double)row[i*64 + l] * (double)av;
            s1 += x; s2 += x * x;
        }
        for (int m = 32; m; m >>= 1) { s1 += __shfl_xor(s1, m); s2 += __shfl_xor(s2, m); }
        if (l == 0) {
            double mean = s1 / (double)D_;
            double var  = s2 / (double)D_ - mean * mean;
            double inv  = 1.0 / sqrt(var + 1e-5);
            stats[tg] = make_float2((float)((double)av * inv), (float)(mean * inv));
        }
    }
}

// ============================================================
// Kernel A: 3-term split GEMM, A-only LDS + B->regs (distance-2 prefetch)
// (R5 resubmit unchanged — R5 bench was an infra failure, no measurement.)
//
// BM=128, BN=256, BK=32, 512 thr (8 waves 2Mx4N, 64x64/wave, 4x4 16x16x32 frags).
// Grid 768 = 128 M x 6 N tiles; hh-MAJOR XCD mapping: each XCD sees <=2
// B-panels (<=2MB hi+lo) -> B stays L2-warm under the A stream (R4's
// failure was 12MB B/XCD evicted by A -> 900cy exposed/step).
//
// Per step t:
//   ds_read A frags (buf t%3)            [8 x b128/wave]
//   DMA A(t+2) -> buf (t+2)%3            [2 x global_load_lds w16]
//   MFMA 3 bursts (B reg set t&1)
//   load B(t+2) -> reg set t&1           [8 x 16B/wave; WAR after MFMA ->
//                                         full-step flight time > HBM lat]
//   vmcnt(10) [leaves this step's A-DMA(2)+B(8)] + barrier
// LDS = 3 x 16KB = 48KB; LDS traffic/step 80KB (was 176KB) << MFMA floor.
// A-ring hazard: DMA(t)->buf (t+2)%3==(t-1)%3, last read start of t-1,
// consumed before end-of-(t-1) barrier -> 1 barrier before DMA. Safe.
// vmcnt ledger: prologue 20 issued, vmcnt(8) keeps B(1); steady state
// <=10 at entry + 10 issued, vmcnt(10) drains exactly the (t+1) group.
// Staging swizzle unchanged (inverse-swizzled src + swizzled ds_read).
// ============================================================
#define ABUF_U 8192          // ushorts per A buffer (Ahi 4096 | Alo 4096)
#define KSTEPS 32

__device__ __forceinline__ void gll16(const unsigned short* g, unsigned short* l)
{
    __builtin_amdgcn_global_load_lds((const __attribute__((address_space(1))) void*)g,
                                     (__attribute__((address_space(3))) void*)l, 16, 0, 0);
}

__launch_bounds__(512, 2)
__global__ void k_scores8(const unsigned short* __restrict__ ahi,
                          const unsigned short* __restrict__ alo,
                          const unsigned short* __restrict__ w1thi,
                          const unsigned short* __restrict__ w1tlo,
                          const float* __restrict__ b1, const float* __restrict__ W2,
                          double* __restrict__ scores)
{
    __shared__ __align__(16) unsigned short smem[3*ABUF_U];   // 48 KiB

    const int tid = threadIdx.x;
    const int blk = blockIdx.x;
    // XCD swizzle, hh-major: lin 0..767; hh = lin/128 (<=2 panels per XCD)
    const int lin = (blk & 7) * 96 + (blk >> 3);
    const int hh = lin >> 7, mm = lin & 127;
    const int t0 = mm * 128;
    const int h0 = hh * 256;

    const int l  = tid & 63, w = tid >> 6;
    const int wr = w >> 2, wcn = w & 3;            // wave row/col group
    const int lm = l & 15, lq = l >> 4;

    // ---- A staging: per-lane global src (inverse-swizzled), wave-uniform LDS dst
    const int lrow  = l >> 2;                      // 0..15 within 16-row chunk
    const int lslot = (l & 3) ^ ((l >> 3) & 3);    // logical 16B slot for phys slot l&3
    const unsigned short* sA_hi = ahi + (size_t)(t0 + w*16 + lrow) * D_ + lslot*8;
    const unsigned short* sA_lo = alo + (size_t)(t0 + w*16 + lrow) * D_ + lslot*8;
    const int dA = w*512;                          // buffer-relative A-hi dst (ushorts)

    // ---- A fragment read offsets (swizzled): phys_slot = lq ^ ((row>>1)&3)
    const int sw8 = (lq ^ ((lm >> 1) & 3)) * 8;
    int offA[4];
    #pragma unroll
    for (int r = 0; r < 4; ++r) offA[r] = (wr*64 + r*16 + lm)*32 + sw8;

    // ---- B fragment global base (per-lane): row = h0+wcn*64+c*16+lm, slot lq
    const unsigned short* bBh = w1thi + (size_t)(h0 + wcn*64 + lm) * D_ + lq*8;
    const unsigned short* bBl = w1tlo + (size_t)(h0 + wcn*64 + lm) * D_ + lq*8;

    f32x4 acc[4][4];
    #pragma unroll
    for (int r = 0; r < 4; ++r)
        #pragma unroll
        for (int c = 0; c < 4; ++c) acc[r][c] = (f32x4){0.f, 0.f, 0.f, 0.f};

    // ---- prologue: DMA A(0)->buf0, A(1)->buf1; load B(0)->set0, B(1)->set1
    bf16x8 bhp[2][4], blp[2][4];
    gll16(sA_hi,      &smem[0*ABUF_U + dA]);
    gll16(sA_lo,      &smem[0*ABUF_U + dA + 4096]);
    gll16(sA_hi + 32, &smem[1*ABUF_U + dA]);
    gll16(sA_lo + 32, &smem[1*ABUF_U + dA + 4096]);
    #pragma unroll
    for (int c = 0; c < 4; ++c) {
        bhp[0][c] = *(const bf16x8*)&bBh[(size_t)c*16*D_];
        blp[0][c] = *(const bf16x8*)&bBl[(size_t)c*16*D_];
    }
    #pragma unroll
    for (int c = 0; c < 4; ++c) {
        bhp[1][c] = *(const bf16x8*)&bBh[(size_t)c*16*D_ + 32];
        blp[1][c] = *(const bf16x8*)&bBl[(size_t)c*16*D_ + 32];
    }
    // drain A(0),A(1),B(0); keep B(1) (8) in flight
    asm volatile("s_waitcnt vmcnt(8)" ::: "memory");
    asm volatile("s_barrier" ::: "memory");

    #pragma unroll
    for (int t = 0; t < KSTEPS; ++t) {
        const int cur = t & 1;
        // A fragment reads for this step (buf t%3)
        bf16x8 ah[4], al[4];
        const int ab = (t % 3) * ABUF_U;
        #pragma unroll
        for (int r = 0; r < 4; ++r) ah[r] = *(const bf16x8*)&smem[ab + offA[r]];
        #pragma unroll
        for (int r = 0; r < 4; ++r) al[r] = *(const bf16x8*)&smem[ab + 4096 + offA[r]];
        // A DMA for step t+2 (ring slot == (t-1)%3: last read at t-1, 1 barrier ago)
        if (t + 2 < KSTEPS) {
            const int ab2 = ((t + 2) % 3) * ABUF_U;
            gll16(sA_hi + (t+2)*32, &smem[ab2 + dA]);
            gll16(sA_lo + (t+2)*32, &smem[ab2 + dA + 4096]);
        }
        // MFMA bursts (term order fixed: hh, hl, lh -> bitwise-stable scores)
        __builtin_amdgcn_s_setprio(1);
        #pragma unroll
        for (int r = 0; r < 4; ++r)
            #pragma unroll
            for (int c = 0; c < 4; ++c)
                acc[r][c] = __builtin_amdgcn_mfma_f32_16x16x32_bf16(ah[r], bhp[cur][c], acc[r][c], 0, 0, 0);
        #pragma unroll
        for (int r = 0; r < 4; ++r)
            #pragma unroll
            for (int c = 0; c < 4; ++c)
                acc[r][c] = __builtin_amdgcn_mfma_f32_16x16x32_bf16(ah[r], blp[cur][c], acc[r][c], 0, 0, 0);
        #pragma unroll
        for (int r = 0; r < 4; ++r)
            #pragma unroll
            for (int c = 0; c < 4; ++c)
                acc[r][c] = __builtin_amdgcn_mfma_f32_16x16x32_bf16(al[r], bhp[cur][c], acc[r][c], 0, 0, 0);
        __builtin_amdgcn_s_setprio(0);
        // B prefetch for t+2 into the set just freed (WAR keeps it after MFMA;
        // full-step flight time before its drain at end of t+1)
        if (t + 2 < KSTEPS) {
            #pragma unroll
            for (int c = 0; c < 4; ++c) {
                bhp[cur][c] = *(const bf16x8*)&bBh[(size_t)c*16*D_ + (t+2)*32];
                blp[cur][c] = *(const bf16x8*)&bBl[(size_t)c*16*D_ + (t+2)*32];
            }
        }
        // drain last step's A-DMA(t+1) + B(t+1); keep this step's 10 in flight
        if (t < KSTEPS - 2)       asm volatile("s_waitcnt vmcnt(10)" ::: "memory");
        else if (t == KSTEPS - 2) asm volatile("s_waitcnt vmcnt(0)" ::: "memory");
        if (t < KSTEPS - 1)       asm volatile("s_barrier" ::: "memory");
    }

    // ---- epilogue: bias + GELU + W2 dot, f64 reduce over h, atomic into scores
    float b1v[4], w2v[4];
    #pragma unroll
    for (int c = 0; c < 4; ++c) {
        int hg = h0 + wcn*64 + c*16 + lm;
        bool ok = (hg < H_);
        b1v[c] = ok ? b1[hg] : 0.0f;
        w2v[c] = ok ? W2[hg] : 0.0f;
    }
    const float is2 = 0.70710678118654752440f;
    #pragma unroll
    for (int r = 0; r < 4; ++r) {
        #pragma unroll
        for (int i = 0; i < 4; ++i) {
            float ps = 0.0f;
            #pragma unroll
            for (int c = 0; c < 4; ++c) {
                float z  = acc[r][c][i] + b1v[c];
                float gl = 0.5f * z * (1.0f + erff(z * is2));
                ps = fmaf(gl, w2v[c], ps);
            }
            double psd = (double)ps;
            psd += __shfl_xor(psd, 1);
            psd += __shfl_xor(psd, 2);
            psd += __shfl_xor(psd, 4);
            psd += __shfl_xor(psd, 8);
            if (lm == 0)
                atomicAdd(&scores[t0 + wr*64 + r*16 + lq*4 + i], psd);
        }
    }
}

// ============================================================
// Kernel A (fallback, smaller-ws version): in-loop LN+split staging
// ============================================================
__launch_bounds__(256)
__global__ void k_scores_fb(const float* __restrict__ emb, const float* __restrict__ ln_g,
                            const float* __restrict__ ln_b, const float2* __restrict__ stats,
                            const unsigned short* __restrict__ w1thi,
                            const unsigned short* __restrict__ w1tlo,
                            const float* __restrict__ b1, const float* __restrict__ W2,
                            double* __restrict__ scores)
{
    __shared__ __align__(16) unsigned short sAhi[128*40];
    __shared__ __align__(16) unsigned short sAlo[128*40];
    __shared__ __align__(16) unsigned short sBhi[128*40];
    __shared__ __align__(16) unsigned short sBlo[128*40];
    __shared__ float sS1[128], sS2[128];

    const int tid = threadIdx.x;
    const int blk = blockIdx.x;
    const int xcd = blk & 7, slot = blk >> 3;
    const int lin = xcd * 176 + slot;
    const int tt = lin / 11, hh = lin - tt * 11;
    const int t0 = tt * 128;
    const int h0 = hh * 128;

    if (tid < 128) {
        float2 st = stats[t0 + tid];
        sS1[tid] = st.x; sS2[tid] = st.y;
    }
    f32x4 acc[4][4];
    #pragma unroll
    for (int r = 0; r < 4; ++r)
        #pragma unroll
        for (int c = 0; c < 4; ++c) acc[r][c] = (f32x4){0.f, 0.f, 0.f, 0.f};
    const int l = tid & 63, w = tid >> 6;
    const int lm = l & 15, lq = l >> 4;
    const int wr = (w >> 1) * 64;
    const int wc = (w & 1) * 64;
    __syncthreads();

    for (int kc = 0; kc < D_; kc += 32) {
        #pragma unroll
        for (int r2 = 0; r2 < 2; ++r2) {
            int g = tid + r2 * 256;
            int row = g >> 2, oct = g & 3;
            size_t src = (size_t)(h0 + row) * D_ + kc + oct * 8;
            int dst = row * 40 + oct * 8;
            *(bf16x8*)&sBhi[dst] = *(const bf16x8*)&w1thi[src];
            *(bf16x8*)&sBlo[dst] = *(const bf16x8*)&w1tlo[src];
        }
        #pragma unroll
        for (int r2 = 0; r2 < 2; ++r2) {
            int g = tid + r2 * 256;
            int tk = g >> 2, oct = g & 3;
            int tg = t0 + tk, dg = kc + oct * 8;
            const float* ep = emb + (size_t)tg * D_ + dg;
            float s1 = sS1[tk], ns2 = -sS2[tk];
            union { unsigned short s[8]; bf16x8 v; } hi, lo;
            #pragma unroll
            for (int j = 0; j < 8; ++j) {
                float t  = fmaf(ep[j], s1, ns2);
                float xn = fmaf(t, ln_g[dg + j], ln_b[dg + j]);
                unsigned short hb = f2bf(xn);
                float hf = __uint_as_float((uint32_t)hb << 16);
                hi.s[j] = hb;
                lo.s[j] = f2bf(xn - hf);
            }
            int dst = tk * 40 + oct * 8;
            *(bf16x8*)&sAhi[dst] = hi.v;
            *(bf16x8*)&sAlo[dst] = lo.v;
        }
        __syncthreads();
        bf16x8 ah[4], al[4], bh[4], bl[4];
        #pragma unroll
        for (int r = 0; r < 4; ++r) {
            int off = (wr + r * 16 + lm) * 40 + lq * 8;
            ah[r] = *(const bf16x8*)&sAhi[off];
            al[r] = *(const bf16x8*)&sAlo[off];
        }
        #pragma unroll
        for (int c = 0; c < 4; ++c) {
            int off = (wc + c * 16 + lm) * 40 + lq * 8;
            bh[c] = *(const bf16x8*)&sBhi[off];
            bl[c] = *(const bf16x8*)&sBlo[off];
        }
        #pragma unroll
        for (int r = 0; r < 4; ++r)
            #pragma unroll
            for (int c = 0; c < 4; ++c) {
                acc[r][c] = __builtin_amdgcn_mfma_f32_16x16x32_bf16(ah[r], bh[c], acc[r][c], 0, 0, 0);
                acc[r][c] = __builtin_amdgcn_mfma_f32_16x16x32_bf16(ah[r], bl[c], acc[r][c], 0, 0, 0);
                acc[r][c] = __builtin_amdgcn_mfma_f32_16x16x32_bf16(al[r], bh[c], acc[r][c], 0, 0, 0);
            }
        __syncthreads();
    }
    float b1v[4], w2v[4];
    #pragma unroll
    for (int c = 0; c < 4; ++c) {
        int hg = h0 + wc + c * 16 + lm;
        bool ok = (hg < H_);
        b1v[c] = ok ? b1[hg] : 0.0f;
        w2v[c] = ok ? W2[hg] : 0.0f;
    }
    const float is2 = 0.70710678118654752440f;
    #pragma unroll
    for (int r = 0; r < 4; ++r) {
        #pragma unroll
        for (int i = 0; i < 4; ++i) {
            float ps = 0.0f;
            #pragma unroll
            for (int c = 0; c < 4; ++c) {
                float z  = acc[r][c][i] + b1v[c];
                float gl = 0.5f * z * (1.0f + erff(z * is2));
                ps = fmaf(gl, w2v[c], ps);
            }
            double psd = (double)ps;
            psd += __shfl_xor(psd, 1);
            psd += __shfl_xor(psd, 2);
            psd += __shfl_xor(psd, 4);
            psd += __shfl_xor(psd, 8);
            if (lm == 0)
                atomicAdd(&scores[t0 + wr + r * 16 + lq * 4 + i], psd);
        }
    }
}

// ============================================================
// JAX threefry2x32
// ============================================================
__device__ inline void tf2x32(uint32_t k0, uint32_t k1, uint32_t x0, uint32_t x1,
                              uint32_t& o0, uint32_t& o1)
{
    const uint32_t ks2 = k0 ^ k1 ^ 0x1BD11BDAu;
    x0 += k0; x1 += k1;
#define ROT_(v,d) (((v) << (d)) | ((v) >> (32 - (d))))
#define RND_(R) { x0 += x1; x1 = ROT_(x1, R); x1 ^= x0; }
    RND_(13) RND_(15) RND_(26) RND_(6)
    x0 += k1;  x1 += ks2 + 1u;
    RND_(17) RND_(29) RND_(16) RND_(24)
    x0 += ks2; x1 += k0 + 2u;
    RND_(13) RND_(15) RND_(26) RND_(6)
    x0 += k0;  x1 += k1 + 3u;
    RND_(17) RND_(29) RND_(16) RND_(24)
    x0 += k1;  x1 += ks2 + 4u;
    RND_(13) RND_(15) RND_(26) RND_(6)
    x0 += ks2; x1 += k0 + 5u;
    o0 = x0; o1 = x1;
#undef RND_
#undef ROT_
}

// ============================================================
// Kernel B: gumbel pert + MSB radix-select k-th largest + indicator counts
// ============================================================
__launch_bounds__(256)
__global__ void k_topk(const double* __restrict__ scores, const float* __restrict__ attn,
                       const float* __restrict__ b2, int* __restrict__ cnt)
{
    __shared__ unsigned long long keys[2048];
    __shared__ unsigned int hist[256];
    __shared__ unsigned int wsum[4];
    __shared__ unsigned int selDigit, selBase;
    __shared__ double red[4];

    const int tid = threadIdx.x;
    const int blk = blockIdx.x;
    const int j = blk / 40;
    const int s = (blk % 40) >> 3;
    const int b = blk & 7;

    uint32_t kk0, kk1;
    tf2x32(0u, 42u, 0u, (uint32_t)j, kk0, kk1);

    double tsum = 0.0;
    for (int t = tid; t < T_; t += 256) tsum += (double)attn[b * T_ + t];
    for (int m = 32; m; m >>= 1) tsum += __shfl_xor(tsum, m);
    if ((tid & 63) == 0) red[tid >> 6] = tsum;
    __syncthreads();
    const double Teff = red[0] + red[1] + red[2] + red[3];
    const float rhos[5] = {0.1f, 0.2f, 0.3f, 0.4f, 0.5f};
    int kst = (int)(rhos[j] * (float)Teff);
    if (kst < 1) kst = 1;

    const double bb2 = (double)b2[0];
    #pragma unroll
    for (int r = 0; r < 8; ++r) {
        int t = tid + r * 256;
        int f = (s * 8 + b) * T_ + t;
        uint32_t o0, o1;
        tf2x32(kk0, kk1, 0u, (uint32_t)f, o0, o1);
        uint32_t bits = o0 ^ o1;
        float u = __uint_as_float((bits >> 9) | 0x3f800000u) - 1.0f;
        float a1 = (float)((double)u + (double)1e-6f);
        float la = (float)log((double)a1);
        float m1 = (float)((double)1e-6f - (double)la);
        float lb = (float)log((double)m1);
        float noise = -lb;
        float av = attn[b * T_ + t];
        double pv = (av == 0.0f) ? -1e9 : (scores[b * T_ + t] + bb2 + (double)noise);
        unsigned long long uu = (unsigned long long)__double_as_longlong(pv);
        keys[t] = (uu >> 63) ? ~uu : (uu | 0x8000000000000000ull);
    }
    __syncthreads();

    unsigned long long pfx = 0;
    unsigned int plo = (unsigned int)(2048 - kst);
    const int lane = tid & 63, wv = tid >> 6;
    for (int pass = 0; pass < 8; ++pass) {
        const int shift = 56 - 8 * pass;
        const unsigned long long maskhi = (pass == 0) ? 0ull : (~0ull << (64 - 8 * pass));
        hist[tid] = 0;
        __syncthreads();
        #pragma unroll
        for (int r = 0; r < 8; ++r) {
            unsigned long long kk = keys[tid + r * 256];
            if ((kk & maskhi) == pfx)
                atomicAdd(&hist[(unsigned int)((kk >> shift) & 255ull)], 1u);
        }
        __syncthreads();
        unsigned int own = hist[tid];
        int val = (int)own;
        #pragma unroll
        for (int off = 1; off < 64; off <<= 1) {
            int n = __shfl_up(val, off);
            if (lane >= off) val += n;
        }
        if (lane == 63) wsum[wv] = (unsigned int)val;
        __syncthreads();
        unsigned int woff = 0;
        for (int q = 0; q < wv; ++q) woff += wsum[q];
        unsigned int incl = (unsigned int)val + woff;
        unsigned int excl = incl - own;
        if (own > 0 && plo >= excl && plo < incl) { selDigit = (unsigned int)tid; selBase = excl; }
        __syncthreads();
        pfx |= ((unsigned long long)selDigit << shift);
        plo -= selBase;
        __syncthreads();
    }

    #pragma unroll
    for (int r = 0; r < 8; ++r) {
        int t = tid + r * 256;
        if (keys[t] >= pfx) atomicAdd(&cnt[(j * 8 + b) * T_ + t], 1);
    }
}

// ============================================================
// Kernel C: finalize g = cnt/5, write g & g_sweep & rho_eff, row sums
// ============================================================
__launch_bounds__(256)
__global__ void k_gfin(const int* __restrict__ cnt, const float* __restrict__ attn,
                       float* __restrict__ out, double* __restrict__ sumeff,
                       double* __restrict__ sumatt, double* __restrict__ sumg)
{
    __shared__ double redA[4], redB[4], redC[4];
    const int j = blockIdx.x >> 3, b = blockIdx.x & 7;
    const int tid = threadIdx.x;
    double sg = 0.0, se = 0.0, sa = 0.0;
    for (int t = tid; t < T_; t += 256) {
        int c = cnt[(j * 8 + b) * T_ + t];
        float g  = (float)c / 5.0f;
        float av = attn[b * T_ + t];
        out[OUT_GSW + (j * 8 + b) * T_ + t] = g;
        if (j == 4) out[OUT_G + b * T_ + t] = g;
        sg += (double)g;
        se += (double)(av * g);
        sa += (double)av;
    }
    for (int m = 32; m; m >>= 1) { sg += __shfl_xor(sg, m); se += __shfl_xor(se, m); sa += __shfl_xor(sa, m); }
    if ((tid & 63) == 0) { redA[tid>>6] = sg; redB[tid>>6] = se; redC[tid>>6] = sa; }
    __syncthreads();
    if (tid == 0) {
        sg = redA[0]+redA[1]+redA[2]+redA[3];
        se = redB[0]+redB[1]+redB[2]+redB[3];
        sa = redC[0]+redC[1]+redC[2]+redC[3];
        sumg[j*8+b] = sg; sumeff[j*8+b] = se;
        if (j == 0) sumatt[b] = sa;
        out[OUT_RHOEFF + j*8 + b] = (float)sg / (float)sa;
    }
}

// ============================================================
// Kernel D: pooled weighted sums over tok = emb_table[ids] (512 blocks)
// ============================================================
__launch_bounds__(256)
__global__ void k_pool(const int* __restrict__ ids, const float* __restrict__ attn,
                       const float* __restrict__ out, const float* __restrict__ emb_table,
                       double* __restrict__ predw, double* __restrict__ fullw)
{
    __shared__ int   sid[128];
    __shared__ float sw[6][128];
    const int blk = blockIdx.x;
    const int b  = blk >> 6;            // 8
    const int dc = (blk >> 4) & 3;      // 4
    const int tc = blk & 15;            // 16
    const int tid = threadIdx.x;
    const int d = dc * 256 + tid;
    if (tid < 128) {
        int t = tc * 128 + tid;
        sid[tid] = ids[b * T_ + t];
        float av = attn[b * T_ + t];
        sw[0][tid] = av;
        #pragma unroll
        for (int j = 0; j < 5; ++j) {
            float g = out[OUT_GSW + (j * 8 + b) * T_ + t];
            sw[1 + j][tid] = av * g;
        }
    }
    __syncthreads();
    double acc[6] = {0,0,0,0,0,0};
    #pragma unroll 4
    for (int i = 0; i < 128; ++i) {
        float val = emb_table[(size_t)sid[i] * D_ + d];
        #pragma unroll
        for (int c = 0; c < 6; ++c) acc[c] += (double)(val * sw[c][i]);
    }
    atomicAdd(&fullw[b * D_ + d], acc[0]);
    #pragma unroll
    for (int j = 0; j < 5; ++j)
        atomicAdd(&predw[(j * 8 + b) * D_ + d], acc[1 + j]);
}

// ============================================================
// Kernel E: losses (5 blocks, one per rho) + finalize
// ============================================================
__launch_bounds__(256)
__global__ void k_loss(const double* __restrict__ predw, const double* __restrict__ fullw,
                       const double* __restrict__ sumeff, const double* __restrict__ sumatt,
                       float* __restrict__ out, double* __restrict__ lrws)
{
    __shared__ double red[4];
    const int j = blockIdx.x;
    const int tid = threadIdx.x;
    double p = 0.0;
    for (int i = tid; i < B_ * D_; i += 256) {
        int b = i >> 10;
        double dF = sumatt[b];        if (dF < 1e-6) dF = 1e-6;
        double dE = sumeff[j*8 + b];  if (dE < 1e-6) dE = 1e-6;
        double diff = predw[j * B_ * D_ + i] / dE - fullw[i] / dF;
        p += diff * diff;
    }
    for (int m = 32; m; m >>= 1) p += __shfl_xor(p, m);
    if ((tid & 63) == 0) red[tid >> 6] = p;
    __syncthreads();
    if (tid == 0) {
        double t = red[0] + red[1] + red[2] + red[3];
        float lr = (float)(t / (double)(B_ * D_));
        out[OUT_LOSS + j] = lr;
        lrws[j] = (double)lr;
    }
}

__launch_bounds__(64)
__global__ void k_lfin(const double* __restrict__ lrws, float* __restrict__ out)
{
    if (threadIdx.x == 0) {
        float srec = 0.0f;
        for (int j = 0; j < 5; ++j) srec += (float)lrws[j];
        out[OUT_RECON] = srec / 5.0f;
    }
}

extern "C" void kernel_launch(void* const* d_in, const int* in_sizes, int n_in,
                              void* d_out, int out_size, void* d_ws, size_t ws_size,
                              hipStream_t stream)
{
    const int*   ids  = (const int*)  d_in[0];
    const float* emb  = (const float*)d_in[1];
    const float* attn = (const float*)d_in[2];
    const float* ln_g = (const float*)d_in[3];
    const float* ln_b = (const float*)d_in[4];
    const float* W1   = (const float*)d_in[5];
    const float* b1   = (const float*)d_in[6];
    const float* W2   = (const float*)d_in[7];
    const float* b2   = (const float*)d_in[8];
    const float* et   = (const float*)d_in[9];
    float* out = (float*)d_out;
    char*  ws  = (char*)d_ws;

    double* scores = (double*)(ws + WS_SCORES);
    int*    cnt    = (int*)   (ws + WS_CNT);
    double* predw  = (double*)(ws + WS_PREDW);
    double* fullw  = (double*)(ws + WS_FULLW);
    double* sumeff = (double*)(ws + WS_SUMEFF);
    double* sumatt = (double*)(ws + WS_SUMATT);
    double* sumg   = (double*)(ws + WS_SUMG);
    double* lrws   = (double*)(ws + WS_LR);
    float2* stats  = (float2*)(ws + WS_STATS);
    unsigned short* w1thi = (unsigned short*)(ws + WS_W1THI);
    unsigned short* w1tlo = (unsigned short*)(ws + WS_W1TLO);
    unsigned short* ahi   = (unsigned short*)(ws + WS_AHI);
    unsigned short* alo   = (unsigned short*)(ws + WS_ALO);

    hipMemsetAsync(d_ws, 0, WS_ZERO_BYTES, stream);

    k_w1t<<<48*32, 256, 0, stream>>>(W1, w1thi, w1tlo);
    if (ws_size >= WS_FULL_END) {
        k_asplit<<<NTOK/64, 256, 0, stream>>>(emb, attn, ln_g, ln_b, ahi, alo);
        k_scores8<<<768, 512, 0, stream>>>(ahi, alo, w1thi, w1tlo, b1, W2, scores);
    } else {
        k_stats<<<NTOK/64, 256, 0, stream>>>(emb, attn, stats);
        k_scores_fb<<<1408, 256, 0, stream>>>(emb, ln_g, ln_b, stats, w1thi, w1tlo,
                                              b1, W2, scores);
    }
    k_topk<<<NRHO * NSAMP * B_, 256, 0, stream>>>(scores, attn, b2, cnt);
    k_gfin<<<NRHO * B_, 256, 0, stream>>>(cnt, attn, out, sumeff, sumatt, sumg);
    k_pool<<<512, 256, 0, stream>>>(ids, attn, out, et, predw, fullw);
    k_loss<<<NRHO, 256, 0, stream>>>(predw, fullw, sumeff, sumatt, out, lrws);
    k_lfin<<<1, 64, 0, stream>>>(lrws, out);
}

// Round 7
// 483.805 us; speedup vs baseline: 1.2296x; 1.1898x over previous
//
#include <hip/hip_runtime.h>
#include <math.h>
#include <stdint.h>

#define B_ 8
#define T_ 2048
#define D_ 1024
#define H_ 1365
#define HPAD 1536
#define NTOK (B_*T_)
#define NSAMP 5
#define NRHO 5

typedef float  f32x4  __attribute__((ext_vector_type(4)));
typedef __bf16 bf16x8 __attribute__((ext_vector_type(8)));

// ---- ws layout (bytes) ----
#define WS_SCORES 0                              // f64 [16384]
#define WS_CNT    (WS_SCORES + NTOK*8)           // int [5*8*2048]
#define WS_PREDW  (WS_CNT + NRHO*B_*T_*4)        // f64 [5][8][1024]
#define WS_FULLW  (WS_PREDW + NRHO*B_*D_*8)      // f64 [8][1024]
#define WS_SUMEFF (WS_FULLW + B_*D_*8)           // f64 [5][8]
#define WS_SUMATT (WS_SUMEFF + NRHO*B_*8)        // f64 [8]
#define WS_SUMG   (WS_SUMATT + B_*8)             // f64 [5][8]
#define WS_LR     (WS_SUMG + NRHO*B_*8)          // f64 [5]
#define WS_ZERO_BYTES (WS_LR + NRHO*8)
#define WS_STATS  WS_ZERO_BYTES                  // float2 [16384] (fallback path)
#define WS_W1THI  (WS_STATS + NTOK*8)            // ushort [1536][1024]
#define WS_W1TLO  (WS_W1THI + (size_t)HPAD*D_*2) // ushort [1536][1024]
#define WS_AHI    (WS_W1TLO + (size_t)HPAD*D_*2) // ushort [16384][1024]
#define WS_ALO    (WS_AHI + (size_t)NTOK*D_*2)   // ushort [16384][1024]
#define WS_FULL_END (WS_ALO + (size_t)NTOK*D_*2)

// ---- out layout (f32 elements) ----
#define OUT_G      0
#define OUT_GSW    16384
#define OUT_RECON  98304
#define OUT_LOSS   98305
#define OUT_RHOEFF 98310

__device__ inline unsigned short f2bf(float x) {   // RNE f32 -> bf16 bits
    uint32_t u = __float_as_uint(x);
    return (unsigned short)((u + 0x7FFFu + ((u >> 16) & 1u)) >> 16);
}

// ============================================================
// Prep: W1 [1024][1365] -> W1T hi/lo bf16 [1536][1024] (k-contiguous, zero-padded)
// ============================================================
__launch_bounds__(256)
__global__ void k_w1t(const float* __restrict__ W1, unsigned short* __restrict__ hi,
                      unsigned short* __restrict__ lo)
{
    __shared__ float tile[32][33];
    const int tid = threadIdx.x;
    const int bk = blockIdx.x & 31;
    const int bh = blockIdx.x >> 5;
    const int k0 = bk * 32, h0 = bh * 32;
    const int a = tid & 31, b = tid >> 5;
    #pragma unroll
    for (int i = 0; i < 4; ++i) {
        int k = k0 + b + i * 8;
        int h = h0 + a;
        tile[b + i*8][a] = (h < H_) ? W1[(size_t)k * H_ + h] : 0.0f;
    }
    __syncthreads();
    #pragma unroll
    for (int i = 0; i < 4; ++i) {
        int hrow = h0 + b + i * 8;
        int kcol = k0 + a;
        float v = tile[a][b + i*8];
        unsigned short hb = f2bf(v);
        float hf = __uint_as_float((uint32_t)hb << 16);
        unsigned short lb = f2bf(v - hf);
        size_t dst = (size_t)hrow * D_ + kcol;
        hi[dst] = hb; lo[dst] = lb;
    }
}

// ============================================================
// Prep: fused LN stats (f64) + f32 transform + bf16 hi/lo split -> Ahi/Alo
// ============================================================
__launch_bounds__(256)
__global__ void k_asplit(const float* __restrict__ emb, const float* __restrict__ attn,
                         const float* __restrict__ ln_g, const float* __restrict__ ln_b,
                         unsigned short* __restrict__ ahi, unsigned short* __restrict__ alo)
{
    const int tid = threadIdx.x, l = tid & 63, w = tid >> 6;
    const int t0 = blockIdx.x * 64;
    for (int tk = w; tk < 64; tk += 4) {
        const int tg = t0 + tk;
        const float av = attn[tg];
        const float* row = emb + (size_t)tg * D_;
        float rv[16];
        double s1 = 0.0, s2 = 0.0;
        #pragma unroll
        for (int i = 0; i < 16; ++i) {
            rv[i] = row[i*64 + l];
            double x = (double)rv[i] * (double)av;
            s1 += x; s2 += x * x;
        }
        for (int m = 32; m; m >>= 1) { s1 += __shfl_xor(s1, m); s2 += __shfl_xor(s2, m); }
        double mean = s1 / (double)D_;
        double var  = s2 / (double)D_ - mean * mean;
        double inv  = 1.0 / sqrt(var + 1e-5);
        float sc  = (float)((double)av * inv);
        float nsh = -(float)(mean * inv);
        #pragma unroll
        for (int i = 0; i < 16; ++i) {
            int k = i * 64 + l;
            float t  = fmaf(rv[i], sc, nsh);
            float xn = fmaf(t, ln_g[k], ln_b[k]);
            unsigned short hb = f2bf(xn);
            float hf = __uint_as_float((uint32_t)hb << 16);
            size_t dst = (size_t)tg * D_ + k;
            ahi[dst] = hb;
            alo[dst] = f2bf(xn - hf);
        }
    }
}

// (fallback path prep: per-token stats only)
__launch_bounds__(256)
__global__ void k_stats(const float* __restrict__ emb, const float* __restrict__ attn,
                        float2* __restrict__ stats)
{
    const int tid = threadIdx.x, l = tid & 63, w = tid >> 6;
    const int t0 = blockIdx.x * 64;
    for (int tk = w; tk < 64; tk += 4) {
        const int tg = t0 + tk;
        const float av = attn[tg];
        const float* row = emb + (size_t)tg * D_;
        double s1 = 0.0, s2 = 0.0;
        #pragma unroll
        for (int i = 0; i < D_/64; ++i) {
            double x = (double)row[i*64 + l] * (double)av;
            s1 += x; s2 += x * x;
        }
        for (int m = 32; m; m >>= 1) { s1 += __shfl_xor(s1, m); s2 += __shfl_xor(s2, m); }
        if (l == 0) {
            double mean = s1 / (double)D_;
            double var  = s2 / (double)D_ - mean * mean;
            double inv  = 1.0 / sqrt(var + 1e-5);
            stats[tg] = make_float2((float)((double)av * inv), (float)(mean * inv));
        }
    }
}

// ============================================================
// Kernel A: 3-term split GEMM with full cross-step register prefetch
//
// BM=128, BN=256, BK=32, 512 thr (8 waves 2Mx4N, 64x64/wave, 4x4 16x16x32 frags).
// Grid 768 = 128 M x 6 N tiles (HPAD=1536), R3's XCD mapping (mm-major per
// XCD chunk: A-panels shared within an XCD; B 12MB/XCD absorbed fine per R3's
// FETCH=115MB). B-in-regs is falsified (R4/R6: FETCH 2x, MfmaUtil 22%).
//
// R7 change (R3 post-mortem: only burst-1 overlapped LDS reads; bursts 2/3
// waited on same-step ds_reads -> pipes serialized, 3850cy/step): symmetric
// 3-ring of 48KB buffers (R2 layout), and prefetch ah/al/bh of step t+1 into
// registers DURING step t. Only bl(t) is read in-step (covered by burst-1's
// ~620cy). Schedule per step t:
//   vmcnt(0)              // drains DMA(t+1): in flight one full step
//   s_barrier             // buf (t+1)%3 globally ready
//   issue DMA(t+2)        // -> buf (t-1)%3: last read >=2 barriers ago
//   read bl(t) [4]        // in-step; forced complete before next barrier
//   read ah/al/bh(t+1) [12] -> other reg set (no consumer this step)
//   48 MFMA on regs(t)    // burst-1 zero lgkm dependency; pipes overlap
// vmcnt ledger: exactly one 6-op DMA group outstanding at each wait.
// Buffers touched in step t: DMA->(t+2)%3, bl->(t)%3, prefetch->(t+1)%3 —
// all distinct mod 3. Staging swizzle unchanged (inverse-swizzled source +
// swizzled ds_read, slot ^= (row>>1)&3) -> 0 bank conflicts.
// ============================================================
#define BUF_U 24576          // ushorts per buffer (Ahi 4K | Alo 4K | Bhi 8K | Blo 8K)
#define KSTEPS 32

__device__ __forceinline__ void gll16(const unsigned short* g, unsigned short* l)
{
    __builtin_amdgcn_global_load_lds((const __attribute__((address_space(1))) void*)g,
                                     (__attribute__((address_space(3))) void*)l, 16, 0, 0);
}

__launch_bounds__(512, 2)
__global__ void k_scores8(const unsigned short* __restrict__ ahi,
                          const unsigned short* __restrict__ alo,
                          const unsigned short* __restrict__ w1thi,
                          const unsigned short* __restrict__ w1tlo,
                          const float* __restrict__ b1, const float* __restrict__ W2,
                          double* __restrict__ scores)
{
    __shared__ __align__(16) unsigned short smem[3*BUF_U];   // 144 KiB

    const int tid = threadIdx.x;
    const int blk = blockIdx.x;
    // XCD-aware swizzle (R3-proven): 96 blocks/XCD, hh fastest within chunk
    const int lin = (blk & 7) * 96 + (blk >> 3);
    const int mm = lin / 6, hh = lin - mm * 6;
    const int t0 = mm * 128;
    const int h0 = hh * 256;

    const int l  = tid & 63, w = tid >> 6;
    const int wr = w >> 2, wcn = w & 3;            // wave row/col group
    const int lm = l & 15, lq = l >> 4;

    // ---- staging: per-lane global src (inverse-swizzled), wave-uniform LDS dst
    const int lrow  = l >> 2;                      // 0..15 within 16-row chunk
    const int lslot = (l & 3) ^ ((l >> 3) & 3);    // logical 16B slot for phys slot l&3
    const unsigned short* sA_hi  = ahi   + (size_t)(t0 + w*16 + lrow) * D_ + lslot*8;
    const unsigned short* sA_lo  = alo   + (size_t)(t0 + w*16 + lrow) * D_ + lslot*8;
    const unsigned short* sB_hi0 = w1thi + (size_t)(h0 + w*32 + lrow) * D_ + lslot*8;
    const unsigned short* sB_hi1 = sB_hi0 + 16*D_;
    const unsigned short* sB_lo0 = w1tlo + (size_t)(h0 + w*32 + lrow) * D_ + lslot*8;
    const unsigned short* sB_lo1 = sB_lo0 + 16*D_;
    const int dAhi  = w*512,           dAlo  = 4096 + w*512;
    const int dBhi0 = 8192 + w*1024,   dBhi1 = dBhi0 + 512;
    const int dBlo0 = 16384 + w*1024,  dBlo1 = dBlo0 + 512;

    // ---- fragment read offsets (swizzled): phys_slot = lq ^ ((row>>1)&3)
    const int sw8 = (lq ^ ((lm >> 1) & 3)) * 8;
    int offA[4], offB[4];
    #pragma unroll
    for (int r = 0; r < 4; ++r) offA[r] = (wr*64 + r*16 + lm)*32 + sw8;
    #pragma unroll
    for (int c = 0; c < 4; ++c) offB[c] = 8192 + (wcn*64 + c*16 + lm)*32 + sw8;

    f32x4 acc[4][4];
    #pragma unroll
    for (int r = 0; r < 4; ++r)
        #pragma unroll
        for (int c = 0; c < 4; ++c) acc[r][c] = (f32x4){0.f, 0.f, 0.f, 0.f};

    // ---- prologue: DMA step0->buf0, step1->buf1; drain step0; prefetch frags(0)
    gll16(sA_hi,       &smem[0*BUF_U + dAhi]);
    gll16(sA_lo,       &smem[0*BUF_U + dAlo]);
    gll16(sB_hi0,      &smem[0*BUF_U + dBhi0]);
    gll16(sB_hi1,      &smem[0*BUF_U + dBhi1]);
    gll16(sB_lo0,      &smem[0*BUF_U + dBlo0]);
    gll16(sB_lo1,      &smem[0*BUF_U + dBlo1]);
    gll16(sA_hi  + 32, &smem[1*BUF_U + dAhi]);
    gll16(sA_lo  + 32, &smem[1*BUF_U + dAlo]);
    gll16(sB_hi0 + 32, &smem[1*BUF_U + dBhi0]);
    gll16(sB_hi1 + 32, &smem[1*BUF_U + dBhi1]);
    gll16(sB_lo0 + 32, &smem[1*BUF_U + dBlo0]);
    gll16(sB_lo1 + 32, &smem[1*BUF_U + dBlo1]);
    asm volatile("s_waitcnt vmcnt(6)" ::: "memory");
    asm volatile("s_barrier" ::: "memory");

    bf16x8 ahp[2][4], alp[2][4], bhp[2][4];
    #pragma unroll
    for (int r = 0; r < 4; ++r) {
        ahp[0][r] = *(const bf16x8*)&smem[offA[r]];
        alp[0][r] = *(const bf16x8*)&smem[offA[r] + 4096];
    }
    #pragma unroll
    for (int c = 0; c < 4; ++c) bhp[0][c] = *(const bf16x8*)&smem[offB[c]];

    #pragma unroll
    for (int t = 0; t < KSTEPS; ++t) {
        const int cur = t & 1, nxt = cur ^ 1;
        // drain DMA(t+1) (one full step in flight), then publish to all waves
        asm volatile("s_waitcnt vmcnt(0)" ::: "memory");
        asm volatile("s_barrier" ::: "memory");
        // DMA for step t+2 -> buf (t+2)%3 == (t-1)%3 (last read >=2 barriers ago)
        if (t + 2 < KSTEPS) {
            const int eb = ((t + 2) % 3) * BUF_U;
            const int ko = (t + 2) * 32;
            gll16(sA_hi  + ko, &smem[eb + dAhi]);
            gll16(sA_lo  + ko, &smem[eb + dAlo]);
            gll16(sB_hi0 + ko, &smem[eb + dBhi0]);
            gll16(sB_hi1 + ko, &smem[eb + dBhi1]);
            gll16(sB_lo0 + ko, &smem[eb + dBlo0]);
            gll16(sB_lo1 + ko, &smem[eb + dBlo1]);
        }
        // in-step B-lo of step t (used by burst 2; burst 1 covers its latency)
        bf16x8 bl[4];
        const int db = (t % 3) * BUF_U;
        #pragma unroll
        for (int c = 0; c < 4; ++c) bl[c] = *(const bf16x8*)&smem[db + offB[c] + 8192];
        // register prefetch of ah/al/bh for step t+1 (no consumer this step)
        if (t + 1 < KSTEPS) {
            const int nb = ((t + 1) % 3) * BUF_U;
            #pragma unroll
            for (int r = 0; r < 4; ++r) {
                ahp[nxt][r] = *(const bf16x8*)&smem[nb + offA[r]];
                alp[nxt][r] = *(const bf16x8*)&smem[nb + offA[r] + 4096];
            }
            #pragma unroll
            for (int c = 0; c < 4; ++c) bhp[nxt][c] = *(const bf16x8*)&smem[nb + offB[c]];
        }
        // MFMA bursts on regs(t): burst 1 has zero lgkm dependency
        __builtin_amdgcn_s_setprio(1);
        #pragma unroll
        for (int r = 0; r < 4; ++r)
            #pragma unroll
            for (int c = 0; c < 4; ++c)
                acc[r][c] = __builtin_amdgcn_mfma_f32_16x16x32_bf16(ahp[cur][r], bhp[cur][c], acc[r][c], 0, 0, 0);
        #pragma unroll
        for (int r = 0; r < 4; ++r)
            #pragma unroll
            for (int c = 0; c < 4; ++c)
                acc[r][c] = __builtin_amdgcn_mfma_f32_16x16x32_bf16(ahp[cur][r], bl[c], acc[r][c], 0, 0, 0);
        #pragma unroll
        for (int r = 0; r < 4; ++r)
            #pragma unroll
            for (int c = 0; c < 4; ++c)
                acc[r][c] = __builtin_amdgcn_mfma_f32_16x16x32_bf16(alp[cur][r], bhp[cur][c], acc[r][c], 0, 0, 0);
        __builtin_amdgcn_s_setprio(0);
    }

    // ---- epilogue: bias + GELU + W2 dot, f64 reduce over h, atomic into scores
    float b1v[4], w2v[4];
    #pragma unroll
    for (int c = 0; c < 4; ++c) {
        int hg = h0 + wcn*64 + c*16 + lm;
        bool ok = (hg < H_);
        b1v[c] = ok ? b1[hg] : 0.0f;
        w2v[c] = ok ? W2[hg] : 0.0f;
    }
    const float is2 = 0.70710678118654752440f;
    #pragma unroll
    for (int r = 0; r < 4; ++r) {
        #pragma unroll
        for (int i = 0; i < 4; ++i) {
            float ps = 0.0f;
            #pragma unroll
            for (int c = 0; c < 4; ++c) {
                float z  = acc[r][c][i] + b1v[c];
                float gl = 0.5f * z * (1.0f + erff(z * is2));
                ps = fmaf(gl, w2v[c], ps);
            }
            double psd = (double)ps;
            psd += __shfl_xor(psd, 1);
            psd += __shfl_xor(psd, 2);
            psd += __shfl_xor(psd, 4);
            psd += __shfl_xor(psd, 8);
            if (lm == 0)
                atomicAdd(&scores[t0 + wr*64 + r*16 + lq*4 + i], psd);
        }
    }
}

// ============================================================
// Kernel A (fallback, smaller-ws version): in-loop LN+split staging
// ============================================================
__launch_bounds__(256)
__global__ void k_scores_fb(const float* __restrict__ emb, const float* __restrict__ ln_g,
                            const float* __restrict__ ln_b, const float2* __restrict__ stats,
                            const unsigned short* __restrict__ w1thi,
                            const unsigned short* __restrict__ w1tlo,
                            const float* __restrict__ b1, const float* __restrict__ W2,
                            double* __restrict__ scores)
{
    __shared__ __align__(16) unsigned short sAhi[128*40];
    __shared__ __align__(16) unsigned short sAlo[128*40];
    __shared__ __align__(16) unsigned short sBhi[128*40];
    __shared__ __align__(16) unsigned short sBlo[128*40];
    __shared__ float sS1[128], sS2[128];

    const int tid = threadIdx.x;
    const int blk = blockIdx.x;
    const int xcd = blk & 7, slot = blk >> 3;
    const int lin = xcd * 176 + slot;
    const int tt = lin / 11, hh = lin - tt * 11;
    const int t0 = tt * 128;
    const int h0 = hh * 128;

    if (tid < 128) {
        float2 st = stats[t0 + tid];
        sS1[tid] = st.x; sS2[tid] = st.y;
    }
    f32x4 acc[4][4];
    #pragma unroll
    for (int r = 0; r < 4; ++r)
        #pragma unroll
        for (int c = 0; c < 4; ++c) acc[r][c] = (f32x4){0.f, 0.f, 0.f, 0.f};
    const int l = tid & 63, w = tid >> 6;
    const int lm = l & 15, lq = l >> 4;
    const int wr = (w >> 1) * 64;
    const int wc = (w & 1) * 64;
    __syncthreads();

    for (int kc = 0; kc < D_; kc += 32) {
        #pragma unroll
        for (int r2 = 0; r2 < 2; ++r2) {
            int g = tid + r2 * 256;
            int row = g >> 2, oct = g & 3;
            size_t src = (size_t)(h0 + row) * D_ + kc + oct * 8;
            int dst = row * 40 + oct * 8;
            *(bf16x8*)&sBhi[dst] = *(const bf16x8*)&w1thi[src];
            *(bf16x8*)&sBlo[dst] = *(const bf16x8*)&w1tlo[src];
        }
        #pragma unroll
        for (int r2 = 0; r2 < 2; ++r2) {
            int g = tid + r2 * 256;
            int tk = g >> 2, oct = g & 3;
            int tg = t0 + tk, dg = kc + oct * 8;
            const float* ep = emb + (size_t)tg * D_ + dg;
            float s1 = sS1[tk], ns2 = -sS2[tk];
            union { unsigned short s[8]; bf16x8 v; } hi, lo;
            #pragma unroll
            for (int j = 0; j < 8; ++j) {
                float t  = fmaf(ep[j], s1, ns2);
                float xn = fmaf(t, ln_g[dg + j], ln_b[dg + j]);
                unsigned short hb = f2bf(xn);
                float hf = __uint_as_float((uint32_t)hb << 16);
                hi.s[j] = hb;
                lo.s[j] = f2bf(xn - hf);
            }
            int dst = tk * 40 + oct * 8;
            *(bf16x8*)&sAhi[dst] = hi.v;
            *(bf16x8*)&sAlo[dst] = lo.v;
        }
        __syncthreads();
        bf16x8 ah[4], al[4], bh[4], bl[4];
        #pragma unroll
        for (int r = 0; r < 4; ++r) {
            int off = (wr + r * 16 + lm) * 40 + lq * 8;
            ah[r] = *(const bf16x8*)&sAhi[off];
            al[r] = *(const bf16x8*)&sAlo[off];
        }
        #pragma unroll
        for (int c = 0; c < 4; ++c) {
            int off = (wc + c * 16 + lm) * 40 + lq * 8;
            bh[c] = *(const bf16x8*)&sBhi[off];
            bl[c] = *(const bf16x8*)&sBlo[off];
        }
        #pragma unroll
        for (int r = 0; r < 4; ++r)
            #pragma unroll
            for (int c = 0; c < 4; ++c) {
                acc[r][c] = __builtin_amdgcn_mfma_f32_16x16x32_bf16(ah[r], bh[c], acc[r][c], 0, 0, 0);
                acc[r][c] = __builtin_amdgcn_mfma_f32_16x16x32_bf16(ah[r], bl[c], acc[r][c], 0, 0, 0);
                acc[r][c] = __builtin_amdgcn_mfma_f32_16x16x32_bf16(al[r], bh[c], acc[r][c], 0, 0, 0);
            }
        __syncthreads();
    }
    float b1v[4], w2v[4];
    #pragma unroll
    for (int c = 0; c < 4; ++c) {
        int hg = h0 + wc + c * 16 + lm;
        bool ok = (hg < H_);
        b1v[c] = ok ? b1[hg] : 0.0f;
        w2v[c] = ok ? W2[hg] : 0.0f;
    }
    const float is2 = 0.70710678118654752440f;
    #pragma unroll
    for (int r = 0; r < 4; ++r) {
        #pragma unroll
        for (int i = 0; i < 4; ++i) {
            float ps = 0.0f;
            #pragma unroll
            for (int c = 0; c < 4; ++c) {
                float z  = acc[r][c][i] + b1v[c];
                float gl = 0.5f * z * (1.0f + erff(z * is2));
                ps = fmaf(gl, w2v[c], ps);
            }
            double psd = (double)ps;
            psd += __shfl_xor(psd, 1);
            psd += __shfl_xor(psd, 2);
            psd += __shfl_xor(psd, 4);
            psd += __shfl_xor(psd, 8);
            if (lm == 0)
                atomicAdd(&scores[t0 + wr + r * 16 + lq * 4 + i], psd);
        }
    }
}

// ============================================================
// JAX threefry2x32
// ============================================================
__device__ inline void tf2x32(uint32_t k0, uint32_t k1, uint32_t x0, uint32_t x1,
                              uint32_t& o0, uint32_t& o1)
{
    const uint32_t ks2 = k0 ^ k1 ^ 0x1BD11BDAu;
    x0 += k0; x1 += k1;
#define ROT_(v,d) (((v) << (d)) | ((v) >> (32 - (d))))
#define RND_(R) { x0 += x1; x1 = ROT_(x1, R); x1 ^= x0; }
    RND_(13) RND_(15) RND_(26) RND_(6)
    x0 += k1;  x1 += ks2 + 1u;
    RND_(17) RND_(29) RND_(16) RND_(24)
    x0 += ks2; x1 += k0 + 2u;
    RND_(13) RND_(15) RND_(26) RND_(6)
    x0 += k0;  x1 += k1 + 3u;
    RND_(17) RND_(29) RND_(16) RND_(24)
    x0 += k1;  x1 += ks2 + 4u;
    RND_(13) RND_(15) RND_(26) RND_(6)
    x0 += ks2; x1 += k0 + 5u;
    o0 = x0; o1 = x1;
#undef RND_
#undef ROT_
}

// ============================================================
// Kernel B: gumbel pert + MSB radix-select k-th largest + indicator counts
// ============================================================
__launch_bounds__(256)
__global__ void k_topk(const double* __restrict__ scores, const float* __restrict__ attn,
                       const float* __restrict__ b2, int* __restrict__ cnt)
{
    __shared__ unsigned long long keys[2048];
    __shared__ unsigned int hist[256];
    __shared__ unsigned int wsum[4];
    __shared__ unsigned int selDigit, selBase;
    __shared__ double red[4];

    const int tid = threadIdx.x;
    const int blk = blockIdx.x;
    const int j = blk / 40;
    const int s = (blk % 40) >> 3;
    const int b = blk & 7;

    uint32_t kk0, kk1;
    tf2x32(0u, 42u, 0u, (uint32_t)j, kk0, kk1);

    double tsum = 0.0;
    for (int t = tid; t < T_; t += 256) tsum += (double)attn[b * T_ + t];
    for (int m = 32; m; m >>= 1) tsum += __shfl_xor(tsum, m);
    if ((tid & 63) == 0) red[tid >> 6] = tsum;
    __syncthreads();
    const double Teff = red[0] + red[1] + red[2] + red[3];
    const float rhos[5] = {0.1f, 0.2f, 0.3f, 0.4f, 0.5f};
    int kst = (int)(rhos[j] * (float)Teff);
    if (kst < 1) kst = 1;

    const double bb2 = (double)b2[0];
    #pragma unroll
    for (int r = 0; r < 8; ++r) {
        int t = tid + r * 256;
        int f = (s * 8 + b) * T_ + t;
        uint32_t o0, o1;
        tf2x32(kk0, kk1, 0u, (uint32_t)f, o0, o1);
        uint32_t bits = o0 ^ o1;
        float u = __uint_as_float((bits >> 9) | 0x3f800000u) - 1.0f;
        float a1 = (float)((double)u + (double)1e-6f);
        float la = (float)log((double)a1);
        float m1 = (float)((double)1e-6f - (double)la);
        float lb = (float)log((double)m1);
        float noise = -lb;
        float av = attn[b * T_ + t];
        double pv = (av == 0.0f) ? -1e9 : (scores[b * T_ + t] + bb2 + (double)noise);
        unsigned long long uu = (unsigned long long)__double_as_longlong(pv);
        keys[t] = (uu >> 63) ? ~uu : (uu | 0x8000000000000000ull);
    }
    __syncthreads();

    unsigned long long pfx = 0;
    unsigned int plo = (unsigned int)(2048 - kst);
    const int lane = tid & 63, wv = tid >> 6;
    for (int pass = 0; pass < 8; ++pass) {
        const int shift = 56 - 8 * pass;
        const unsigned long long maskhi = (pass == 0) ? 0ull : (~0ull << (64 - 8 * pass));
        hist[tid] = 0;
        __syncthreads();
        #pragma unroll
        for (int r = 0; r < 8; ++r) {
            unsigned long long kk = keys[tid + r * 256];
            if ((kk & maskhi) == pfx)
                atomicAdd(&hist[(unsigned int)((kk >> shift) & 255ull)], 1u);
        }
        __syncthreads();
        unsigned int own = hist[tid];
        int val = (int)own;
        #pragma unroll
        for (int off = 1; off < 64; off <<= 1) {
            int n = __shfl_up(val, off);
            if (lane >= off) val += n;
        }
        if (lane == 63) wsum[wv] = (unsigned int)val;
        __syncthreads();
        unsigned int woff = 0;
        for (int q = 0; q < wv; ++q) woff += wsum[q];
        unsigned int incl = (unsigned int)val + woff;
        unsigned int excl = incl - own;
        if (own > 0 && plo >= excl && plo < incl) { selDigit = (unsigned int)tid; selBase = excl; }
        __syncthreads();
        pfx |= ((unsigned long long)selDigit << shift);
        plo -= selBase;
        __syncthreads();
    }

    #pragma unroll
    for (int r = 0; r < 8; ++r) {
        int t = tid + r * 256;
        if (keys[t] >= pfx) atomicAdd(&cnt[(j * 8 + b) * T_ + t], 1);
    }
}

// ============================================================
// Kernel C: finalize g = cnt/5, write g & g_sweep & rho_eff, row sums
// ============================================================
__launch_bounds__(256)
__global__ void k_gfin(const int* __restrict__ cnt, const float* __restrict__ attn,
                       float* __restrict__ out, double* __restrict__ sumeff,
                       double* __restrict__ sumatt, double* __restrict__ sumg)
{
    __shared__ double redA[4], redB[4], redC[4];
    const int j = blockIdx.x >> 3, b = blockIdx.x & 7;
    const int tid = threadIdx.x;
    double sg = 0.0, se = 0.0, sa = 0.0;
    for (int t = tid; t < T_; t += 256) {
        int c = cnt[(j * 8 + b) * T_ + t];
        float g  = (float)c / 5.0f;
        float av = attn[b * T_ + t];
        out[OUT_GSW + (j * 8 + b) * T_ + t] = g;
        if (j == 4) out[OUT_G + b * T_ + t] = g;
        sg += (double)g;
        se += (double)(av * g);
        sa += (double)av;
    }
    for (int m = 32; m; m >>= 1) { sg += __shfl_xor(sg, m); se += __shfl_xor(se, m); sa += __shfl_xor(sa, m); }
    if ((tid & 63) == 0) { redA[tid>>6] = sg; redB[tid>>6] = se; redC[tid>>6] = sa; }
    __syncthreads();
    if (tid == 0) {
        sg = redA[0]+redA[1]+redA[2]+redA[3];
        se = redB[0]+redB[1]+redB[2]+redB[3];
        sa = redC[0]+redC[1]+redC[2]+redC[3];
        sumg[j*8+b] = sg; sumeff[j*8+b] = se;
        if (j == 0) sumatt[b] = sa;
        out[OUT_RHOEFF + j*8 + b] = (float)sg / (float)sa;
    }
}

// ============================================================
// Kernel D: pooled weighted sums over tok = emb_table[ids] (512 blocks)
// ============================================================
__launch_bounds__(256)
__global__ void k_pool(const int* __restrict__ ids, const float* __restrict__ attn,
                       const float* __restrict__ out, const float* __restrict__ emb_table,
                       double* __restrict__ predw, double* __restrict__ fullw)
{
    __shared__ int   sid[128];
    __shared__ float sw[6][128];
    const int blk = blockIdx.x;
    const int b  = blk >> 6;            // 8
    const int dc = (blk >> 4) & 3;      // 4
    const int tc = blk & 15;            // 16
    const int tid = threadIdx.x;
    const int d = dc * 256 + tid;
    if (tid < 128) {
        int t = tc * 128 + tid;
        sid[tid] = ids[b * T_ + t];
        float av = attn[b * T_ + t];
        sw[0][tid] = av;
        #pragma unroll
        for (int j = 0; j < 5; ++j) {
            float g = out[OUT_GSW + (j * 8 + b) * T_ + t];
            sw[1 + j][tid] = av * g;
        }
    }
    __syncthreads();
    double acc[6] = {0,0,0,0,0,0};
    #pragma unroll 4
    for (int i = 0; i < 128; ++i) {
        float val = emb_table[(size_t)sid[i] * D_ + d];
        #pragma unroll
        for (int c = 0; c < 6; ++c) acc[c] += (double)(val * sw[c][i]);
    }
    atomicAdd(&fullw[b * D_ + d], acc[0]);
    #pragma unroll
    for (int j = 0; j < 5; ++j)
        atomicAdd(&predw[(j * 8 + b) * D_ + d], acc[1 + j]);
}

// ============================================================
// Kernel E: losses (5 blocks, one per rho) + finalize
// ============================================================
__launch_bounds__(256)
__global__ void k_loss(const double* __restrict__ predw, const double* __restrict__ fullw,
                       const double* __restrict__ sumeff, const double* __restrict__ sumatt,
                       float* __restrict__ out, double* __restrict__ lrws)
{
    __shared__ double red[4];
    const int j = blockIdx.x;
    const int tid = threadIdx.x;
    double p = 0.0;
    for (int i = tid; i < B_ * D_; i += 256) {
        int b = i >> 10;
        double dF = sumatt[b];        if (dF < 1e-6) dF = 1e-6;
        double dE = sumeff[j*8 + b];  if (dE < 1e-6) dE = 1e-6;
        double diff = predw[j * B_ * D_ + i] / dE - fullw[i] / dF;
        p += diff * diff;
    }
    for (int m = 32; m; m >>= 1) p += __shfl_xor(p, m);
    if ((tid & 63) == 0) red[tid >> 6] = p;
    __syncthreads();
    if (tid == 0) {
        double t = red[0] + red[1] + red[2] + red[3];
        float lr = (float)(t / (double)(B_ * D_));
        out[OUT_LOSS + j] = lr;
        lrws[j] = (double)lr;
    }
}

__launch_bounds__(64)
__global__ void k_lfin(const double* __restrict__ lrws, float* __restrict__ out)
{
    if (threadIdx.x == 0) {
        float srec = 0.0f;
        for (int j = 0; j < 5; ++j) srec += (float)lrws[j];
        out[OUT_RECON] = srec / 5.0f;
    }
}

extern "C" void kernel_launch(void* const* d_in, const int* in_sizes, int n_in,
                              void* d_out, int out_size, void* d_ws, size_t ws_size,
                              hipStream_t stream)
{
    const int*   ids  = (const int*)  d_in[0];
    const float* emb  = (const float*)d_in[1];
    const float* attn = (const float*)d_in[2];
    const float* ln_g = (const float*)d_in[3];
    const float* ln_b = (const float*)d_in[4];
    const float* W1   = (const float*)d_in[5];
    const float* b1   = (const float*)d_in[6];
    const float* W2   = (const float*)d_in[7];
    const float* b2   = (const float*)d_in[8];
    const float* et   = (const float*)d_in[9];
    float* out = (float*)d_out;
    char*  ws  = (char*)d_ws;

    double* scores = (double*)(ws + WS_SCORES);
    int*    cnt    = (int*)   (ws + WS_CNT);
    double* predw  = (double*)(ws + WS_PREDW);
    double* fullw  = (double*)(ws + WS_FULLW);
    double* sumeff = (double*)(ws + WS_SUMEFF);
    double* sumatt = (double*)(ws + WS_SUMATT);
    double* sumg   = (double*)(ws + WS_SUMG);
    double* lrws   = (double*)(ws + WS_LR);
    float2* stats  = (float2*)(ws + WS_STATS);
    unsigned short* w1thi = (unsigned short*)(ws + WS_W1THI);
    unsigned short* w1tlo = (unsigned short*)(ws + WS_W1TLO);
    unsigned short* ahi   = (unsigned short*)(ws + WS_AHI);
    unsigned short* alo   = (unsigned short*)(ws + WS_ALO);

    hipMemsetAsync(d_ws, 0, WS_ZERO_BYTES, stream);

    k_w1t<<<48*32, 256, 0, stream>>>(W1, w1thi, w1tlo);
    if (ws_size >= WS_FULL_END) {
        k_asplit<<<NTOK/64, 256, 0, stream>>>(emb, attn, ln_g, ln_b, ahi, alo);
        k_scores8<<<768, 512, 0, stream>>>(ahi, alo, w1thi, w1tlo, b1, W2, scores);
    } else {
        k_stats<<<NTOK/64, 256, 0, stream>>>(emb, attn, stats);
        k_scores_fb<<<1408, 256, 0, stream>>>(emb, ln_g, ln_b, stats, w1thi, w1tlo,
                                              b1, W2, scores);
    }
    k_topk<<<NRHO * NSAMP * B_, 256, 0, stream>>>(scores, attn, b2, cnt);
    k_gfin<<<NRHO * B_, 256, 0, stream>>>(cnt, attn, out, sumeff, sumatt, sumg);
    k_pool<<<512, 256, 0, stream>>>(ids, attn, out, et, predw, fullw);
    k_loss<<<NRHO, 256, 0, stream>>>(predw, fullw, sumeff, sumatt, out, lrws);
    k_lfin<<<1, 64, 0, stream>>>(lrws, out);
}